// Round 2
// baseline (961.936 us; speedup 1.0000x reference)
//
#include <hip/hip_runtime.h>
#include <hip/hip_bf16.h>

typedef __hip_bfloat16 bf16;

#define S  3
#define V  25
#define C  64
#define O  64
#define IC 16
#define NN 32
#define TT 256

__device__ __forceinline__ float b2f(bf16 v) { return __bfloat162float(v); }

// dtype-adaptive load: f32 flag chooses float32 vs bfloat16 interpretation
__device__ __forceinline__ float ldv(const void* p, size_t i, int f32) {
    return f32 ? ((const float*)p)[i] : b2f(((const bf16*)p)[i]);
}

// ---------------------------------------------------------------------------
// Kernel 0: detect input dtype. If x is really float32, reading it as bf16
// yields garbage magnitudes/NaNs among even elements with certainty over 2048
// samples; bf16 normal(0,1) data never exceeds ~6.
// ---------------------------------------------------------------------------
__global__ void k_detect(const void* __restrict__ x, int* __restrict__ flag) {
    if (threadIdx.x == 0) {
        const bf16* p = (const bf16*)x;
        int f32 = 0;
        for (int i = 0; i < 2048; i++) {
            float v = b2f(p[i]);
            if (!(v > -1000.f && v < 1000.f)) { f32 = 1; break; }  // huge or NaN
        }
        *flag = f32;
    }
}

// ---------------------------------------------------------------------------
// Kernel 1: A_comb[s,u,v] = w0*A + w1*softmax(PA, axis=-1)
// ---------------------------------------------------------------------------
__global__ void k_acomb(const void* __restrict__ A, const void* __restrict__ PA,
                        const void* __restrict__ wA, float* __restrict__ A_comb,
                        const int* __restrict__ flagp) {
    int f32 = *flagp;
    int r = threadIdx.x;           // one row (s,u) per thread, 75 rows
    if (r >= S * V) return;
    float w0 = ldv(wA, 0, f32), w1 = ldv(wA, 1, f32);
    float vals[V];
    float m = -1e30f;
    for (int v = 0; v < V; v++) { vals[v] = ldv(PA, r * V + v, f32); m = fmaxf(m, vals[v]); }
    float sum = 0.f;
    for (int v = 0; v < V; v++) { vals[v] = __expf(vals[v] - m); sum += vals[v]; }
    float inv = 1.f / sum;
    float* outp = A_comb + r * V;
    for (int v = 0; v < V; v++) outp[v] = w0 * ldv(A, r * V + v, f32) + w1 * vals[v] * inv;
}

// ---------------------------------------------------------------------------
// Kernel 2: S1[s,n,u,v] += sum_t qa[t,u,:]·kb[t,v,:]   (partial over t-chunks)
// ---------------------------------------------------------------------------
#define TCH 32
__global__ __launch_bounds__(256) void k_s1(
    const void* __restrict__ x,
    const void* __restrict__ Wa, const void* __restrict__ ba,
    const void* __restrict__ Wb, const void* __restrict__ bb,
    float* __restrict__ S1g, const int* __restrict__ flagp) {
    int f32 = *flagp;
    int tchunk = blockIdx.x, n = blockIdx.y, s = blockIdx.z;
    int tid = threadIdx.x;

    __shared__ float wa[C][IC + 1], wb[C][IC + 1];
    __shared__ float bas[IC], bbs[IC];
    __shared__ float xs[V][68];
    __shared__ float qa[V][IC + 1], kb[V][IC + 1];

    for (int w = tid; w < C * IC; w += 256) {
        int c = w / IC, i = w % IC;
        wa[c][i] = ldv(Wa, (size_t)(s * C + c) * IC + i, f32);
        wb[c][i] = ldv(Wb, (size_t)(s * C + c) * IC + i, f32);
    }
    if (tid < IC) {
        bas[tid] = ldv(ba, s * IC + tid, f32);
        bbs[tid] = ldv(bb, s * IC + tid, f32);
    }

    float acc[3] = {0.f, 0.f, 0.f};
    int t0 = tchunk * TCH;
    for (int t = t0; t < t0 + TCH; t++) {
        __syncthreads();                       // xs/qa/kb consumers done; weights ready
        size_t xbase = (size_t)((n * TT + t) * V) * C;
        for (int w = tid; w < V * C; w += 256) xs[w / C][w % C] = ldv(x, xbase + w, f32);
        __syncthreads();
        for (int w = tid; w < 2 * V * IC; w += 256) {
            int sel = w / (V * IC);
            int r = w % (V * IC);
            int u = r / IC, i = r % IC;
            float a = sel ? bbs[i] : bas[i];
            const float(*W)[IC + 1] = sel ? wb : wa;
            for (int c = 0; c < C; c++) a += xs[u][c] * W[c][i];
            if (sel) kb[u][i] = a; else qa[u][i] = a;
        }
        __syncthreads();
        for (int j = 0; j < 3; j++) {
            int p = tid + j * 256;
            if (p < V * V) {
                int u = p / V, v = p % V;
                float e = 0.f;
                for (int i = 0; i < IC; i++) e += qa[u][i] * kb[v][i];
                acc[j] += e;
            }
        }
    }
    for (int j = 0; j < 3; j++) {
        int p = tid + j * 256;
        if (p < V * V) atomicAdd(&S1g[(size_t)(s * NN + n) * V * V + p], acc[j]);
    }
}

// ---------------------------------------------------------------------------
// Kernel 3: in-place A1[s,n,u,:] = softmax(S1[s,n,u,:] / 64)
// ---------------------------------------------------------------------------
__global__ void k_a1(float* __restrict__ S1g) {
    int sn = blockIdx.x;
    int u = threadIdx.x;
    if (u >= V) return;
    float* row = S1g + (size_t)sn * V * V + u * V;
    const float scale = 1.0f / 64.0f;      // 1/sqrt(IC*T)
    float vals[V];
    float m = -1e30f;
    for (int v = 0; v < V; v++) { vals[v] = row[v] * scale; m = fmaxf(m, vals[v]); }
    float sum = 0.f;
    for (int v = 0; v < V; v++) { vals[v] = __expf(vals[v] - m); sum += vals[v]; }
    float inv = 1.f / sum;
    for (int v = 0; v < V; v++) row[v] = vals[v] * inv;
}

// ---------------------------------------------------------------------------
// Kernel 4: per (n,t): qa/kb -> A2 softmax -> A_in -> z -> y (sum over s)
//           -> BN -> +x residual -> relu -> out (dtype per flag)
// ---------------------------------------------------------------------------
__global__ __launch_bounds__(256) void k_main(
    const void* __restrict__ x,
    const void* __restrict__ Wa, const void* __restrict__ ba,
    const void* __restrict__ Wb, const void* __restrict__ bb,
    const void* __restrict__ Wd, const void* __restrict__ bd,
    const void* __restrict__ gamma, const void* __restrict__ beta,
    const void* __restrict__ wA,
    const float* __restrict__ A_comb, const float* __restrict__ A1g,
    void* __restrict__ outp, const int* __restrict__ flagp) {
    int f32 = *flagp;
    int nt = blockIdx.x;
    int n = nt / TT, t = nt % TT;
    int tid = threadIdx.x;

    __shared__ float xs[V][68];
    __shared__ float qa[V][IC + 1], kb[V][IC + 1];
    __shared__ float Ain[V][V + 1];
    __shared__ float zs[V][68];
    __shared__ float wd[C][O];
    __shared__ float wa[C][IC + 1], wb[C][IC + 1];
    __shared__ float bas[IC], bbs[IC];

    float w2 = ldv(wA, 2, f32), w3 = ldv(wA, 3, f32);

    size_t xbase = (size_t)(n * TT + t) * V * C;
    for (int w = tid; w < V * C; w += 256) xs[w / C][w % C] = ldv(x, xbase + w, f32);

    float yacc[7];
    for (int j = 0; j < 7; j++) yacc[j] = 0.f;

    for (int s = 0; s < S; s++) {
        __syncthreads();   // prior-iter consumers of wa/wb/wd done; xs ready on s=0
        for (int w = tid; w < C * IC; w += 256) {
            int c = w / IC, i = w % IC;
            wa[c][i] = ldv(Wa, (size_t)(s * C + c) * IC + i, f32);
            wb[c][i] = ldv(Wb, (size_t)(s * C + c) * IC + i, f32);
        }
        for (int w = tid; w < C * O; w += 256)
            wd[w / O][w % O] = ldv(Wd, (size_t)s * C * O + w, f32);
        if (tid < IC) {
            bas[tid] = ldv(ba, s * IC + tid, f32);
            bbs[tid] = ldv(bb, s * IC + tid, f32);
        }
        __syncthreads();

        // qa/kb projections: (V x IC) = (25x64)@(64x16) + bias
        for (int w = tid; w < 2 * V * IC; w += 256) {
            int sel = w / (V * IC);
            int r = w % (V * IC);
            int u = r / IC, i = r % IC;
            float a = sel ? bbs[i] : bas[i];
            const float(*W)[IC + 1] = sel ? wb : wa;
            for (int c = 0; c < C; c++) a += xs[u][c] * W[c][i];
            if (sel) kb[u][i] = a; else qa[u][i] = a;
        }
        __syncthreads();

        // E[u,v] = qa_u . kb_v, scaled 1/sqrt(IC)
        for (int w = tid; w < V * V; w += 256) {
            int u = w / V, v = w % V;
            float e = 0.f;
            for (int i = 0; i < IC; i++) e += qa[u][i] * kb[v][i];
            Ain[u][v] = e * 0.25f;
        }
        __syncthreads();

        // row softmax -> A2; combine A_in = A_comb + w2*A1 + w3*A2
        if (tid < V) {
            int u = tid;
            float m = -1e30f;
            for (int v = 0; v < V; v++) m = fmaxf(m, Ain[u][v]);
            float p[V], sum = 0.f;
            for (int v = 0; v < V; v++) { p[v] = __expf(Ain[u][v] - m); sum += p[v]; }
            float inv = 1.f / sum;
            const float* ac = A_comb + (size_t)(s * V + u) * V;
            const float* a1 = A1g + (size_t)((s * NN + n) * V + u) * V;
            for (int v = 0; v < V; v++) Ain[u][v] = ac[v] + w2 * a1[v] + w3 * p[v] * inv;
        }
        __syncthreads();

        // z[u,c] = sum_v A_in[u,v] * x[v,c]
        for (int w = tid; w < V * C; w += 256) {
            int u = w / C, c = w % C;
            float z = 0.f;
            for (int v = 0; v < V; v++) z += Ain[u][v] * xs[v][c];
            zs[u][c] = z;
        }
        __syncthreads();

        // y[u,o] += sum_c z[u,c] * Wd[c,o]
        for (int j = 0; j < 7; j++) {
            int w = tid + j * 256;
            if (w < V * O) {
                int u = w / O, o = w % O;
                float a = yacc[j];
                for (int c = 0; c < C; c++) a += zs[u][c] * wd[c][o];
                yacc[j] = a;
            }
        }
    }

    // epilogue: + bd.sum(0), BN (mean0/var1), + x residual, relu
    const float inv_bn = rsqrtf(1.0f + 1e-5f);
    size_t obase = (size_t)(n * TT + t) * V * O;
    for (int j = 0; j < 7; j++) {
        int w = tid + j * 256;
        if (w < V * O) {
            int u = w / O, o = w % O;
            float bsum = ldv(bd, o, f32) + ldv(bd, O + o, f32) + ldv(bd, 2 * O + o, f32);
            float g = ldv(gamma, o, f32) * inv_bn;
            float bt = ldv(beta, o, f32);
            float yv = (yacc[j] + bsum) * g + bt + xs[u][o];
            yv = fmaxf(yv, 0.f);
            if (f32) ((float*)outp)[obase + w] = yv;
            else     ((bf16*)outp)[obase + w] = __float2bfloat16(yv);
        }
    }
}

// ---------------------------------------------------------------------------
extern "C" void kernel_launch(void* const* d_in, const int* in_sizes, int n_in,
                              void* d_out, int out_size, void* d_ws, size_t ws_size,
                              hipStream_t stream) {
    const void* x     = d_in[0];
    const void* A     = d_in[1];
    const void* PA    = d_in[2];
    const void* wA    = d_in[3];
    const void* Wa    = d_in[4];
    const void* ba    = d_in[5];
    const void* Wb    = d_in[6];
    const void* bb    = d_in[7];
    const void* Wd    = d_in[8];
    const void* bd    = d_in[9];
    const void* gamma = d_in[10];
    const void* beta  = d_in[11];

    int*   flagp  = (int*)d_ws;
    float* wsf    = (float*)d_ws;
    float* A_comb = wsf + 64;              // 1875 floats
    float* S1     = wsf + 64 + 2048;       // 60000 floats, reused in-place as A1

    hipMemsetAsync(S1, 0, (size_t)S * NN * V * V * sizeof(float), stream);
    k_detect<<<1, 64, 0, stream>>>(x, flagp);
    k_acomb<<<1, 128, 0, stream>>>(A, PA, wA, A_comb, flagp);
    k_s1<<<dim3(TT / TCH, NN, S), 256, 0, stream>>>(x, Wa, ba, Wb, bb, S1, flagp);
    k_a1<<<S * NN, 64, 0, stream>>>(S1);
    k_main<<<NN * TT, 256, 0, stream>>>(x, Wa, ba, Wb, bb, Wd, bd, gamma, beta, wA,
                                        A_comb, S1, d_out, flagp);
}

// Round 3
// 592.903 us; speedup vs baseline: 1.6224x; 1.6224x over previous
//
#include <hip/hip_runtime.h>
#include <hip/hip_bf16.h>

typedef __hip_bfloat16 bf16;

#define S  3
#define V  25
#define C  64
#define O  64
#define IC 16
#define NN 32
#define TT 256
#define TB 2
#define TCH 32

__device__ __forceinline__ float b2f(bf16 v) { return __bfloat162float(v); }

// dtype-adaptive load: f32 flag chooses float32 vs bfloat16 interpretation
__device__ __forceinline__ float ldv(const void* p, size_t i, int f32) {
    return f32 ? ((const float*)p)[i] : b2f(((const bf16*)p)[i]);
}

// ---------------------------------------------------------------------------
// Kernel 0: dtype detect (unchanged from passing version)
// ---------------------------------------------------------------------------
__global__ void k_detect(const void* __restrict__ x, int* __restrict__ flag) {
    if (threadIdx.x == 0) {
        const bf16* p = (const bf16*)x;
        int f32 = 0;
        for (int i = 0; i < 2048; i++) {
            float v = b2f(p[i]);
            if (!(v > -1000.f && v < 1000.f)) { f32 = 1; break; }
        }
        *flag = f32;
    }
}

// ---------------------------------------------------------------------------
// Kernel 1: A_comb[s,u,v] = w0*A + w1*softmax(PA, axis=-1)
// ---------------------------------------------------------------------------
__global__ void k_acomb(const void* __restrict__ A, const void* __restrict__ PA,
                        const void* __restrict__ wA, float* __restrict__ A_comb,
                        const int* __restrict__ flagp) {
    int f32 = *flagp;
    int r = threadIdx.x;
    if (r >= S * V) return;
    float w0 = ldv(wA, 0, f32), w1 = ldv(wA, 1, f32);
    float vals[V];
    float m = -1e30f;
    for (int v = 0; v < V; v++) { vals[v] = ldv(PA, r * V + v, f32); m = fmaxf(m, vals[v]); }
    float sum = 0.f;
    for (int v = 0; v < V; v++) { vals[v] = __expf(vals[v] - m); sum += vals[v]; }
    float inv = 1.f / sum;
    float* outp = A_comb + r * V;
    for (int v = 0; v < V; v++) outp[v] = w0 * ldv(A, r * V + v, f32) + w1 * vals[v] * inv;
}

// ---------------------------------------------------------------------------
// Kernel 2: S1[s,n,u,v] += sum_t qa[t,u,:]·kb[t,v,:]  — float4-tiled, dbuf x
// ---------------------------------------------------------------------------
__global__ __launch_bounds__(256) void k_s1(
    const void* __restrict__ x,
    const void* __restrict__ Wa, const void* __restrict__ ba,
    const void* __restrict__ Wb, const void* __restrict__ bb,
    float* __restrict__ S1g, const int* __restrict__ flagp) {
    int f32 = *flagp;
    int tchunk = blockIdx.x, n = blockIdx.y, s = blockIdx.z;
    int tid = threadIdx.x;

    __shared__ __align__(16) float xs[2][V][68];
    __shared__ __align__(16) float wat[IC][68], wbt[IC][68];
    __shared__ __align__(16) float qa[V][20], kb[V][20];
    __shared__ float bas[IC], bbs[IC];

    // transposed weight staging: wat[i][c] = Wa[s][c][i]
    if (f32) {
        const float4* Wa4 = (const float4*)Wa + s * 256;
        const float4* Wb4 = (const float4*)Wb + s * 256;
        for (int j = tid; j < 512; j += 256) {
            int sel = j >> 8, jj = j & 255;
            int c = jj >> 2, i0 = (jj & 3) * 4;
            float4 v = sel ? Wb4[jj] : Wa4[jj];
            float (*W)[68] = sel ? wbt : wat;
            W[i0 + 0][c] = v.x; W[i0 + 1][c] = v.y; W[i0 + 2][c] = v.z; W[i0 + 3][c] = v.w;
        }
    } else {
        for (int w = tid; w < 2048; w += 256) {
            int sel = w >> 10, ww = w & 1023;
            (sel ? wbt : wat)[ww & 15][ww >> 4] = ldv(sel ? Wb : Wa, (size_t)s * 1024 + ww, 0);
        }
    }
    if (tid < IC) { bas[tid] = ldv(ba, s * IC + tid, f32); bbs[tid] = ldv(bb, s * IC + tid, f32); }

    int t0 = tchunk * TCH;
    if (f32) {
        const float4* xp = (const float4*)x + (size_t)(n * TT + t0) * 400;
        for (int w = tid; w < 400; w += 256)
            *(float4*)&xs[0][w >> 4][(w & 15) * 4] = xp[w];
    } else {
        size_t base = (size_t)(n * TT + t0) * V * C;
        for (int w = tid; w < 1600; w += 256) xs[0][w >> 6][w & 63] = ldv(x, base + w, 0);
    }
    __syncthreads();

    float acc[3] = {0.f, 0.f, 0.f};
    for (int tt = 0; tt < TCH; tt++) {
        int cur = tt & 1;
        // proj: 800 tasks (sel,u,i), float4 over c
        for (int w = tid; w < 800; w += 256) {
            int sel = w / 400, r = w % 400, u = r >> 4, i = r & 15;
            float a = sel ? bbs[i] : bas[i];
            const float* Wr = sel ? wbt[i] : wat[i];
            const float* xr = xs[cur][u];
            #pragma unroll
            for (int c4 = 0; c4 < 16; c4++) {
                float4 xv = *(const float4*)&xr[c4 * 4];
                float4 wv = *(const float4*)&Wr[c4 * 4];
                a += xv.x * wv.x + xv.y * wv.y + xv.z * wv.z + xv.w * wv.w;
            }
            (sel ? kb : qa)[u][i] = a;
        }
        // stage next t into the other buffer (no conflict with proj reads)
        if (tt + 1 < TCH) {
            int nxt = cur ^ 1;
            if (f32) {
                const float4* xp = (const float4*)x + (size_t)(n * TT + t0 + tt + 1) * 400;
                for (int w = tid; w < 400; w += 256)
                    *(float4*)&xs[nxt][w >> 4][(w & 15) * 4] = xp[w];
            } else {
                size_t base = (size_t)(n * TT + t0 + tt + 1) * V * C;
                for (int w = tid; w < 1600; w += 256) xs[nxt][w >> 6][w & 63] = ldv(x, base + w, 0);
            }
        }
        __syncthreads();
        // E accumulate: 625 tasks
        #pragma unroll
        for (int j = 0; j < 3; j++) {
            int p = tid + j * 256;
            if (p < 625) {
                int u = p / 25, v = p % 25;
                float e = 0.f;
                #pragma unroll
                for (int i4 = 0; i4 < 4; i4++) {
                    float4 qv = *(const float4*)&qa[u][i4 * 4];
                    float4 kv = *(const float4*)&kb[v][i4 * 4];
                    e += qv.x * kv.x + qv.y * kv.y + qv.z * kv.z + qv.w * kv.w;
                }
                acc[j] += e;
            }
        }
        __syncthreads();
    }
    #pragma unroll
    for (int j = 0; j < 3; j++) {
        int p = tid + j * 256;
        if (p < 625) atomicAdd(&S1g[(size_t)(s * NN + n) * 625 + p], acc[j]);
    }
}

// ---------------------------------------------------------------------------
// Kernel 3: in-place A1 = softmax(S1 / 64)
// ---------------------------------------------------------------------------
__global__ void k_a1(float* __restrict__ S1g) {
    int sn = blockIdx.x;
    int u = threadIdx.x;
    if (u >= V) return;
    float* row = S1g + (size_t)sn * V * V + u * V;
    const float scale = 1.0f / 64.0f;
    float vals[V];
    float m = -1e30f;
    for (int v = 0; v < V; v++) { vals[v] = row[v] * scale; m = fmaxf(m, vals[v]); }
    float sum = 0.f;
    for (int v = 0; v < V; v++) { vals[v] = __expf(vals[v] - m); sum += vals[v]; }
    float inv = 1.f / sum;
    for (int v = 0; v < V; v++) row[v] = vals[v] * inv;
}

// ---------------------------------------------------------------------------
// Kernel 4: per (n, t-pair): proj -> E -> softmax/combine -> xw=x·Wd ->
//           y += A_in·xw (over s) -> BN -> residual -> relu
// ---------------------------------------------------------------------------
__global__ __launch_bounds__(256) void k_main(
    const void* __restrict__ x,
    const void* __restrict__ Wa, const void* __restrict__ ba,
    const void* __restrict__ Wb, const void* __restrict__ bb,
    const void* __restrict__ Wd, const void* __restrict__ bd,
    const void* __restrict__ gamma, const void* __restrict__ beta,
    const void* __restrict__ wA,
    const float* __restrict__ A_comb, const float* __restrict__ A1g,
    void* __restrict__ outp, const int* __restrict__ flagp) {
    int f32 = *flagp;
    int bx = blockIdx.x;
    int n = bx >> 7, tc = bx & 127;   // TT/TB = 128
    int t0 = tc * TB;
    int tid = threadIdx.x;

    __shared__ __align__(16) float xs[TB][V][68];       // 3400 f
    __shared__ __align__(16) float wat[IC][68], wbt[IC][68]; // 2176 f
    __shared__ __align__(16) float wd[C][O];            // 4096 f
    __shared__ __align__(16) float pool[TB * V * 68];   // 3400 f: qa/kb, then xw
    __shared__ float Ain[TB][V][26];                    // 1300 f
    __shared__ float bas[IC], bbs[IC];
    __shared__ float gs[O], bts[O], bds[O];

    float (*qa)[V][20] = (float (*)[V][20])pool;            // 1000 f
    float (*kb)[V][20] = (float (*)[V][20])(pool + 1000);   // 1000 f
    float (*xw)[V][68] = (float (*)[V][68])pool;            // 3400 f (aliases qa/kb)

    // stage x for both t
    if (f32) {
        const float4* xp = (const float4*)x + (size_t)(n * TT + t0) * 400;
        for (int w = tid; w < 800; w += 256) {
            int t = w / 400, r = w % 400;
            *(float4*)&xs[t][r >> 4][(r & 15) * 4] = xp[w];
        }
    } else {
        size_t base = (size_t)(n * TT + t0) * V * C;
        for (int w = tid; w < 3200; w += 256)
            xs[w / 1600][(w % 1600) >> 6][w & 63] = ldv(x, base + w, 0);
    }
    if (tid < O) {
        bds[tid] = ldv(bd, tid, f32) + ldv(bd, O + tid, f32) + ldv(bd, 2 * O + tid, f32);
        gs[tid] = ldv(gamma, tid, f32) * rsqrtf(1.f + 1e-5f);
        bts[tid] = ldv(beta, tid, f32);
    }
    float w2 = ldv(wA, 2, f32), w3 = ldv(wA, 3, f32);

    float4 yacc[4];
    #pragma unroll
    for (int j = 0; j < 4; j++) yacc[j] = make_float4(0.f, 0.f, 0.f, 0.f);

    for (int s = 0; s < S; s++) {
        __syncthreads();   // y-phase of prev s done before weight/pool overwrite
        if (f32) {
            const float4* Wa4 = (const float4*)Wa + s * 256;
            const float4* Wb4 = (const float4*)Wb + s * 256;
            for (int j = tid; j < 512; j += 256) {
                int sel = j >> 8, jj = j & 255;
                int c = jj >> 2, i0 = (jj & 3) * 4;
                float4 v = sel ? Wb4[jj] : Wa4[jj];
                float (*W)[68] = sel ? wbt : wat;
                W[i0 + 0][c] = v.x; W[i0 + 1][c] = v.y; W[i0 + 2][c] = v.z; W[i0 + 3][c] = v.w;
            }
            const float4* Wd4 = (const float4*)Wd + s * 1024;
            float4* wd4 = (float4*)wd;
            for (int j = tid; j < 1024; j += 256) wd4[j] = Wd4[j];
        } else {
            for (int w = tid; w < 2048; w += 256) {
                int sel = w >> 10, ww = w & 1023;
                (sel ? wbt : wat)[ww & 15][ww >> 4] = ldv(sel ? Wb : Wa, (size_t)s * 1024 + ww, 0);
            }
            for (int w = tid; w < 4096; w += 256) wd[w >> 6][w & 63] = ldv(Wd, (size_t)s * 4096 + w, 0);
        }
        if (tid < IC) { bas[tid] = ldv(ba, s * IC + tid, f32); bbs[tid] = ldv(bb, s * IC + tid, f32); }
        __syncthreads();

        // proj: 1600 tasks (t, sel, u, i)
        for (int w = tid; w < 1600; w += 256) {
            int t = w / 800, r = w % 800;
            int sel = r / 400, r2 = r % 400, u = r2 >> 4, i = r2 & 15;
            float a = sel ? bbs[i] : bas[i];
            const float* Wr = sel ? wbt[i] : wat[i];
            const float* xr = xs[t][u];
            #pragma unroll
            for (int c4 = 0; c4 < 16; c4++) {
                float4 xv = *(const float4*)&xr[c4 * 4];
                float4 wv = *(const float4*)&Wr[c4 * 4];
                a += xv.x * wv.x + xv.y * wv.y + xv.z * wv.z + xv.w * wv.w;
            }
            (sel ? kb : qa)[t][u][i] = a;
        }
        __syncthreads();

        // E: 1250 tasks
        for (int w = tid; w < 1250; w += 256) {
            int t = w / 625, r = w % 625, u = r / 25, v = r % 25;
            float e = 0.f;
            #pragma unroll
            for (int i4 = 0; i4 < 4; i4++) {
                float4 qv = *(const float4*)&qa[t][u][i4 * 4];
                float4 kv = *(const float4*)&kb[t][v][i4 * 4];
                e += qv.x * kv.x + qv.y * kv.y + qv.z * kv.z + qv.w * kv.w;
            }
            Ain[t][u][v] = e * 0.25f;
        }
        __syncthreads();

        // softmax + combine: 50 rows
        if (tid < TB * V) {
            int t = tid / V, u = tid % V;
            float* row = Ain[t][u];
            float m = -1e30f;
            for (int v = 0; v < V; v++) m = fmaxf(m, row[v]);
            float p[V], sum = 0.f;
            for (int v = 0; v < V; v++) { p[v] = __expf(row[v] - m); sum += p[v]; }
            float inv = 1.f / sum;
            const float* ac = A_comb + (size_t)(s * V + u) * V;
            const float* a1 = A1g + (size_t)((s * NN + n) * V + u) * V;
            for (int v = 0; v < V; v++) row[v] = ac[v] + w2 * a1[v] + w3 * p[v] * inv;
        }
        __syncthreads();

        // xw[t][v][o] = sum_c x[t,v,c]*Wd[c,o]  (overwrites dead qa/kb)
        for (int w = tid; w < 800; w += 256) {
            int t = w / 400, r = w % 400, v = r >> 4, oq = r & 15;
            float4 a2 = make_float4(0.f, 0.f, 0.f, 0.f);
            const float* xr = xs[t][v];
            #pragma unroll
            for (int c = 0; c < C; c++) {
                float xv = xr[c];
                float4 wv = *(const float4*)&wd[c][oq * 4];
                a2.x += xv * wv.x; a2.y += xv * wv.y; a2.z += xv * wv.z; a2.w += xv * wv.w;
            }
            *(float4*)&xw[t][v][oq * 4] = a2;
        }
        __syncthreads();

        // y[t][u][o] += sum_v Ain[t,u,v]*xw[t,v,o]  (fixed thread->task map)
        #pragma unroll
        for (int rr = 0; rr < 4; rr++) {
            int w = tid + rr * 256;
            if (w < 800) {
                int t = w / 400, r = w % 400, u = r >> 4, oq = r & 15;
                float4 a3 = yacc[rr];
                const float* arow = Ain[t][u];
                #pragma unroll
                for (int v = 0; v < V; v++) {
                    float av = arow[v];
                    float4 xv = *(const float4*)&xw[t][v][oq * 4];
                    a3.x += av * xv.x; a3.y += av * xv.y; a3.z += av * xv.z; a3.w += av * xv.w;
                }
                yacc[rr] = a3;
            }
        }
        // loop-top __syncthreads protects xw/Ain until all threads finish
    }

    // epilogue
    #pragma unroll
    for (int rr = 0; rr < 4; rr++) {
        int w = tid + rr * 256;
        if (w < 800) {
            int t = w / 400, r = w % 400, u = r >> 4, oq = r & 15;
            int o0 = oq * 4;
            float4 a = yacc[rr];
            float v0 = fmaxf((a.x + bds[o0 + 0]) * gs[o0 + 0] + bts[o0 + 0] + xs[t][u][o0 + 0], 0.f);
            float v1 = fmaxf((a.y + bds[o0 + 1]) * gs[o0 + 1] + bts[o0 + 1] + xs[t][u][o0 + 1], 0.f);
            float v2 = fmaxf((a.z + bds[o0 + 2]) * gs[o0 + 2] + bts[o0 + 2] + xs[t][u][o0 + 2], 0.f);
            float v3 = fmaxf((a.w + bds[o0 + 3]) * gs[o0 + 3] + bts[o0 + 3] + xs[t][u][o0 + 3], 0.f);
            size_t ob = (size_t)((n * TT + t0 + t) * V + u) * O + o0;
            if (f32) {
                *(float4*)((float*)outp + ob) = make_float4(v0, v1, v2, v3);
            } else {
                bf16* op = (bf16*)outp;
                op[ob + 0] = __float2bfloat16(v0);
                op[ob + 1] = __float2bfloat16(v1);
                op[ob + 2] = __float2bfloat16(v2);
                op[ob + 3] = __float2bfloat16(v3);
            }
        }
    }
}

// ---------------------------------------------------------------------------
extern "C" void kernel_launch(void* const* d_in, const int* in_sizes, int n_in,
                              void* d_out, int out_size, void* d_ws, size_t ws_size,
                              hipStream_t stream) {
    const void* x     = d_in[0];
    const void* A     = d_in[1];
    const void* PA    = d_in[2];
    const void* wA    = d_in[3];
    const void* Wa    = d_in[4];
    const void* ba    = d_in[5];
    const void* Wb    = d_in[6];
    const void* bb    = d_in[7];
    const void* Wd    = d_in[8];
    const void* bd    = d_in[9];
    const void* gamma = d_in[10];
    const void* beta  = d_in[11];

    int*   flagp  = (int*)d_ws;
    float* wsf    = (float*)d_ws;
    float* A_comb = wsf + 64;              // 1875 floats
    float* S1     = wsf + 64 + 2048;       // 60000 floats, reused in-place as A1

    hipMemsetAsync(S1, 0, (size_t)S * NN * V * V * sizeof(float), stream);
    k_detect<<<1, 64, 0, stream>>>(x, flagp);
    k_acomb<<<1, 128, 0, stream>>>(A, PA, wA, A_comb, flagp);
    k_s1<<<dim3(TT / TCH, NN, S), 256, 0, stream>>>(x, Wa, ba, Wb, bb, S1, flagp);
    k_a1<<<S * NN, 64, 0, stream>>>(S1);
    k_main<<<NN * TT / TB, 256, 0, stream>>>(x, Wa, ba, Wb, bb, Wd, bd, gamma, beta, wA,
                                             A_comb, S1, d_out, flagp);
}

// Round 4
// 549.539 us; speedup vs baseline: 1.7504x; 1.0789x over previous
//
#include <hip/hip_runtime.h>
#include <hip/hip_bf16.h>

typedef __hip_bfloat16 bf16;

#define S  3
#define V  25
#define C  64
#define O  64
#define IC 16
#define NN 32
#define TT 256
#define TB 2
#define TCH 32

__device__ __forceinline__ float b2f(bf16 v) { return __bfloat162float(v); }

__device__ __forceinline__ float ldv(const void* p, size_t i, int f32) {
    return f32 ? ((const float*)p)[i] : b2f(((const bf16*)p)[i]);
}

__device__ __forceinline__ void fma4(float4& a, float s, float4 b) {
    a.x += s * b.x; a.y += s * b.y; a.z += s * b.z; a.w += s * b.w;
}

// dot of two 16-float vectors, both 16B-aligned (f4 loads)
__device__ __forceinline__ float dot16v(const float* a, const float* b) {
    float4 a0 = *(const float4*)(a + 0),  a1 = *(const float4*)(a + 4);
    float4 a2 = *(const float4*)(a + 8),  a3 = *(const float4*)(a + 12);
    float4 b0 = *(const float4*)(b + 0),  b1 = *(const float4*)(b + 4);
    float4 b2 = *(const float4*)(b + 8),  b3 = *(const float4*)(b + 12);
    float e = a0.x*b0.x + a0.y*b0.y + a0.z*b0.z + a0.w*b0.w;
    e += a1.x*b1.x + a1.y*b1.y + a1.z*b1.z + a1.w*b1.w;
    e += a2.x*b2.x + a2.y*b2.y + a2.z*b2.z + a2.w*b2.w;
    e += a3.x*b3.x + a3.y*b3.y + a3.z*b3.z + a3.w*b3.w;
    return e;
}

// ---------------------------------------------------------------------------
__global__ void k_detect(const void* __restrict__ x, int* __restrict__ flag) {
    if (threadIdx.x == 0) {
        const bf16* p = (const bf16*)x;
        int f32 = 0;
        for (int i = 0; i < 2048; i++) {
            float v = b2f(p[i]);
            if (!(v > -1000.f && v < 1000.f)) { f32 = 1; break; }
        }
        *flag = f32;
    }
}

// ---------------------------------------------------------------------------
__global__ void k_acomb(const void* __restrict__ A, const void* __restrict__ PA,
                        const void* __restrict__ wA, float* __restrict__ A_comb,
                        const int* __restrict__ flagp) {
    int f32 = *flagp;
    int r = threadIdx.x;
    if (r >= S * V) return;
    float w0 = ldv(wA, 0, f32), w1 = ldv(wA, 1, f32);
    float vals[V];
    float m = -1e30f;
    for (int v = 0; v < V; v++) { vals[v] = ldv(PA, r * V + v, f32); m = fmaxf(m, vals[v]); }
    float sum = 0.f;
    for (int v = 0; v < V; v++) { vals[v] = __expf(vals[v] - m); sum += vals[v]; }
    float inv = 1.f / sum;
    float* outp = A_comb + r * V;
    for (int v = 0; v < V; v++) outp[v] = w0 * ldv(A, r * V + v, f32) + w1 * vals[v] * inv;
}

// ---------------------------------------------------------------------------
// k_s1: S1[s,n,u,v] += sum_t qa·kb  — register-blocked, 2 t per iteration
// ---------------------------------------------------------------------------
__global__ __launch_bounds__(256) void k_s1(
    const void* __restrict__ x,
    const void* __restrict__ Wa, const void* __restrict__ ba,
    const void* __restrict__ Wb, const void* __restrict__ bb,
    float* __restrict__ S1g, const int* __restrict__ flagp) {
    int f32 = *flagp;
    int tchunk = blockIdx.x, n = blockIdx.y, s = blockIdx.z;
    int tid = threadIdx.x;

    __shared__ __align__(16) float xs[2][V][68];
    __shared__ __align__(16) float was[C][IC], wbs[C][IC];
    __shared__ __align__(16) float qa[2][V][20], kb[2][V][20];
    __shared__ __align__(16) float bas[IC], bbs[IC];

    // natural-layout weight staging
    if (f32) {
        const float4* Wa4 = (const float4*)Wa + s * 256;
        const float4* Wb4 = (const float4*)Wb + s * 256;
        if (tid < 256) { ((float4*)was)[tid] = Wa4[tid]; ((float4*)wbs)[tid] = Wb4[tid]; }
    } else {
        for (int w = tid; w < 1024; w += 256) {
            ((float*)was)[w] = ldv(Wa, (size_t)s * 1024 + w, 0);
            ((float*)wbs)[w] = ldv(Wb, (size_t)s * 1024 + w, 0);
        }
    }
    if (tid < IC) { bas[tid] = ldv(ba, s * IC + tid, f32); bbs[tid] = ldv(bb, s * IC + tid, f32); }

    float acc[2][2] = {{0.f, 0.f}, {0.f, 0.f}};
    int t0 = tchunk * TCH;
    for (int tt = 0; tt < TCH; tt += 2) {
        __syncthreads();   // prior E readers done; weights visible (first iter)
        if (f32) {
            const float4* xp = (const float4*)x + (size_t)(n * TT + t0 + tt) * 400;
            for (int w = tid; w < 800; w += 256) {
                int t = w / 400, r = w % 400;
                *(float4*)&xs[t][r >> 4][(r & 15) * 4] = xp[w];
            }
        } else {
            size_t base = (size_t)(n * TT + t0 + tt) * V * C;
            for (int w = tid; w < 3200; w += 256)
                xs[w / 1600][(w % 1600) >> 6][w & 63] = ldv(x, base + w, 0);
        }
        __syncthreads();
        // proj: 100 tasks (u, iq), each computes 2t x {qa,kb} x 4i
        if (tid < 100) {
            int u = tid >> 2, iq = tid & 3;
            float4 bq = *(const float4*)&bas[iq * 4];
            float4 bk = *(const float4*)&bbs[iq * 4];
            float4 aq0 = bq, aq1 = bq, ak0 = bk, ak1 = bk;
            #pragma unroll
            for (int c4 = 0; c4 < 16; c4++) {
                float4 xv0 = *(const float4*)&xs[0][u][c4 * 4];
                float4 xv1 = *(const float4*)&xs[1][u][c4 * 4];
                float x0a[4], x1a[4];
                *(float4*)x0a = xv0; *(float4*)x1a = xv1;
                #pragma unroll
                for (int k = 0; k < 4; k++) {
                    float4 wav = *(const float4*)&was[c4 * 4 + k][iq * 4];
                    float4 wbv = *(const float4*)&wbs[c4 * 4 + k][iq * 4];
                    fma4(aq0, x0a[k], wav); fma4(aq1, x1a[k], wav);
                    fma4(ak0, x0a[k], wbv); fma4(ak1, x1a[k], wbv);
                }
            }
            *(float4*)&qa[0][u][iq * 4] = aq0;
            *(float4*)&qa[1][u][iq * 4] = aq1;
            *(float4*)&kb[0][u][iq * 4] = ak0;
            *(float4*)&kb[1][u][iq * 4] = ak1;
        }
        __syncthreads();
        // E accumulate: 325 tasks (u, v-pair), summed over both t
        #pragma unroll
        for (int j = 0; j < 2; j++) {
            int w = tid + j * 256;
            if (w < 325) {
                int u = w / 13, v = (w % 13) * 2;
                #pragma unroll
                for (int t = 0; t < 2; t++) {
                    acc[j][0] += dot16v(qa[t][u], kb[t][v]);
                    if (v + 1 < V) acc[j][1] += dot16v(qa[t][u], kb[t][v + 1]);
                }
            }
        }
    }
    #pragma unroll
    for (int j = 0; j < 2; j++) {
        int w = tid + j * 256;
        if (w < 325) {
            int u = w / 13, v = (w % 13) * 2;
            size_t base = (size_t)(s * NN + n) * 625 + u * 25 + v;
            atomicAdd(&S1g[base], acc[j][0]);
            if (v + 1 < V) atomicAdd(&S1g[base + 1], acc[j][1]);
        }
    }
}

// ---------------------------------------------------------------------------
__global__ void k_a1(float* __restrict__ S1g) {
    int sn = blockIdx.x;
    int u = threadIdx.x;
    if (u >= V) return;
    float* row = S1g + (size_t)sn * V * V + u * V;
    const float scale = 1.0f / 64.0f;
    float vals[V];
    float m = -1e30f;
    for (int v = 0; v < V; v++) { vals[v] = row[v] * scale; m = fmaxf(m, vals[v]); }
    float sum = 0.f;
    for (int v = 0; v < V; v++) { vals[v] = __expf(vals[v] - m); sum += vals[v]; }
    float inv = 1.f / sum;
    for (int v = 0; v < V; v++) row[v] = vals[v] * inv;
}

// ---------------------------------------------------------------------------
// k_main: per (n, t-pair): proj -> E+exp -> rowsum -> combine -> z=Ain·x ->
//         y += z·Wd (over s) -> BN -> residual -> relu
// ---------------------------------------------------------------------------
__global__ __launch_bounds__(256) void k_main(
    const void* __restrict__ x,
    const void* __restrict__ Wa, const void* __restrict__ ba,
    const void* __restrict__ Wb, const void* __restrict__ bb,
    const void* __restrict__ Wd, const void* __restrict__ bd,
    const void* __restrict__ gamma, const void* __restrict__ beta,
    const void* __restrict__ wA,
    const float* __restrict__ A_comb, const float* __restrict__ A1g,
    void* __restrict__ outp, const int* __restrict__ flagp) {
    int f32 = *flagp;
    int bx = blockIdx.x;
    int n = bx >> 7, tc = bx & 127;
    int t0 = tc * TB;
    int tid = threadIdx.x;

    __shared__ __align__(16) float xs[TB][V][68];     // 13600 B
    __shared__ __align__(16) float was[C][IC];        //  4096 B
    __shared__ __align__(16) float wbs[C][IC];        //  4096 B
    __shared__ __align__(16) float wds[C][O];         // 16384 B
    __shared__ __align__(16) float pool[TB * V * 68]; // 13600 B: qa/kb, then z
    __shared__ float Ain[TB][V][26];                  //  5200 B
    __shared__ float ac1[V][26];                      //  2600 B
    __shared__ float sinv[TB][V];
    __shared__ __align__(16) float bas[IC], bbs[IC];
    __shared__ float gs[O], bts[O], bds[O];

    // pool offsets: qa[t] at t*500 + u*20; kb[t] at 1000 + t*500 + u*20;
    //               z[t]  at t*1700 + u*68

    if (f32) {
        const float4* xp = (const float4*)x + (size_t)(n * TT + t0) * 400;
        for (int w = tid; w < 800; w += 256) {
            int t = w / 400, r = w % 400;
            *(float4*)&xs[t][r >> 4][(r & 15) * 4] = xp[w];
        }
    } else {
        size_t base = (size_t)(n * TT + t0) * V * C;
        for (int w = tid; w < 3200; w += 256)
            xs[w / 1600][(w % 1600) >> 6][w & 63] = ldv(x, base + w, 0);
    }
    if (tid < O) {
        bds[tid] = ldv(bd, tid, f32) + ldv(bd, O + tid, f32) + ldv(bd, 2 * O + tid, f32);
        gs[tid] = ldv(gamma, tid, f32) * rsqrtf(1.f + 1e-5f);
        bts[tid] = ldv(beta, tid, f32);
    }
    float w2 = ldv(wA, 2, f32), w3 = ldv(wA, 3, f32);

    float4 yac[4];
    #pragma unroll
    for (int j = 0; j < 4; j++) yac[j] = make_float4(0.f, 0.f, 0.f, 0.f);

    for (int s = 0; s < S; s++) {
        __syncthreads();   // y2 readers of pool / weight readers done
        if (f32) {
            const float4* Wa4 = (const float4*)Wa + s * 256;
            const float4* Wb4 = (const float4*)Wb + s * 256;
            if (tid < 256) { ((float4*)was)[tid] = Wa4[tid]; ((float4*)wbs)[tid] = Wb4[tid]; }
            const float4* Wd4 = (const float4*)Wd + s * 1024;
            for (int j = tid; j < 1024; j += 256) ((float4*)wds)[j] = Wd4[j];
        } else {
            for (int w = tid; w < 1024; w += 256) {
                ((float*)was)[w] = ldv(Wa, (size_t)s * 1024 + w, 0);
                ((float*)wbs)[w] = ldv(Wb, (size_t)s * 1024 + w, 0);
            }
            for (int w = tid; w < 4096; w += 256) ((float*)wds)[w] = ldv(Wd, (size_t)s * 4096 + w, 0);
        }
        if (tid < IC) { bas[tid] = ldv(ba, s * IC + tid, f32); bbs[tid] = ldv(bb, s * IC + tid, f32); }
        {   // ac1 = A_comb[s] + w2*A1[s,n]
            const float* acp = A_comb + (size_t)s * 625;
            const float* a1p = A1g + (size_t)(s * NN + n) * 625;
            for (int w = tid; w < 625; w += 256)
                ac1[w / 25][w % 25] = acp[w] + w2 * a1p[w];
        }
        __syncthreads();

        // proj: 100 tasks (u, iq), 2t x {qa,kb} x 4i each
        if (tid < 100) {
            int u = tid >> 2, iq = tid & 3;
            float4 bq = *(const float4*)&bas[iq * 4];
            float4 bk = *(const float4*)&bbs[iq * 4];
            float4 aq0 = bq, aq1 = bq, ak0 = bk, ak1 = bk;
            #pragma unroll
            for (int c4 = 0; c4 < 16; c4++) {
                float4 xv0 = *(const float4*)&xs[0][u][c4 * 4];
                float4 xv1 = *(const float4*)&xs[1][u][c4 * 4];
                float x0a[4], x1a[4];
                *(float4*)x0a = xv0; *(float4*)x1a = xv1;
                #pragma unroll
                for (int k = 0; k < 4; k++) {
                    float4 wav = *(const float4*)&was[c4 * 4 + k][iq * 4];
                    float4 wbv = *(const float4*)&wbs[c4 * 4 + k][iq * 4];
                    fma4(aq0, x0a[k], wav); fma4(aq1, x1a[k], wav);
                    fma4(ak0, x0a[k], wbv); fma4(ak1, x1a[k], wbv);
                }
            }
            *(float4*)&pool[u * 20 + iq * 4] = aq0;
            *(float4*)&pool[500 + u * 20 + iq * 4] = aq1;
            *(float4*)&pool[1000 + u * 20 + iq * 4] = ak0;
            *(float4*)&pool[1500 + u * 20 + iq * 4] = ak1;
        }
        __syncthreads();

        // E + exp (no max-sub; |E/4| << 88): 650 tasks (t, u, v-pair)
        for (int w = tid; w < 650; w += 256) {
            int t = w / 325, r = w % 325, u = r / 13, v = (r % 13) * 2;
            const float* qr = &pool[t * 500 + u * 20];
            const float* k0 = &pool[1000 + t * 500 + v * 20];
            Ain[t][u][v] = __expf(dot16v(qr, k0) * 0.25f);
            if (v + 1 < V) Ain[t][u][v + 1] = __expf(dot16v(qr, k0 + 20) * 0.25f);
        }
        __syncthreads();

        // rowsum -> sinv = w3 / sum
        if (tid < TB * V) {
            int t = tid / V, u = tid % V;
            float sm = 0.f;
            for (int v = 0; v < V; v++) sm += Ain[t][u][v];
            sinv[t][u] = w3 / sm;
        }
        __syncthreads();

        // combine: Ain = ac1 + sinv * p
        for (int w = tid; w < 1250; w += 256) {
            int t = w / 625, r = w % 625, u = r / 25, v = r % 25;
            Ain[t][u][v] = ac1[u][v] + sinv[t][u] * Ain[t][u][v];
        }
        __syncthreads();

        // z[t][u][c] = sum_v Ain[t][u][v] * x[t][v][c]  (z overwrites dead qa/kb)
        for (int w = tid; w < 800; w += 256) {
            int t = w / 400, r = w % 400, u = r >> 4, c4 = r & 15;
            float4 a = make_float4(0.f, 0.f, 0.f, 0.f);
            const float* arow = Ain[t][u];
            #pragma unroll
            for (int v = 0; v < V; v++)
                fma4(a, arow[v], *(const float4*)&xs[t][v][c4 * 4]);
            *(float4*)&pool[t * 1700 + u * 68 + c4 * 4] = a;
        }
        __syncthreads();

        // y += z·Wd: 224 tasks (t, ublk4, oq), 4u x 4o register tile
        if (tid < 224) {
            int t = tid / 112, r = tid % 112, ub = r >> 4, oq = r & 15;
            int u0 = ub * 4;
            #pragma unroll
            for (int c4 = 0; c4 < 16; c4++) {
                float4 wr[4];
                #pragma unroll
                for (int k = 0; k < 4; k++) wr[k] = *(const float4*)&wds[c4 * 4 + k][oq * 4];
                #pragma unroll
                for (int j = 0; j < 4; j++) {
                    if (u0 + j < V) {
                        float4 zv = *(const float4*)&pool[t * 1700 + (u0 + j) * 68 + c4 * 4];
                        fma4(yac[j], zv.x, wr[0]); fma4(yac[j], zv.y, wr[1]);
                        fma4(yac[j], zv.z, wr[2]); fma4(yac[j], zv.w, wr[3]);
                    }
                }
            }
        }
        // loop-top barrier protects pool/weights until all readers finish
    }

    // epilogue
    if (tid < 224) {
        int t = tid / 112, r = tid % 112, ub = r >> 4, oq = r & 15;
        int u0 = ub * 4, o0 = oq * 4;
        #pragma unroll
        for (int j = 0; j < 4; j++) {
            int u = u0 + j;
            if (u < V) {
                float av[4];
                *(float4*)av = yac[j];
                float r0 = fmaxf((av[0] + bds[o0 + 0]) * gs[o0 + 0] + bts[o0 + 0] + xs[t][u][o0 + 0], 0.f);
                float r1 = fmaxf((av[1] + bds[o0 + 1]) * gs[o0 + 1] + bts[o0 + 1] + xs[t][u][o0 + 1], 0.f);
                float r2 = fmaxf((av[2] + bds[o0 + 2]) * gs[o0 + 2] + bts[o0 + 2] + xs[t][u][o0 + 2], 0.f);
                float r3 = fmaxf((av[3] + bds[o0 + 3]) * gs[o0 + 3] + bts[o0 + 3] + xs[t][u][o0 + 3], 0.f);
                size_t ob = (size_t)((n * TT + t0 + t) * V + u) * O + o0;
                if (f32) {
                    *(float4*)((float*)outp + ob) = make_float4(r0, r1, r2, r3);
                } else {
                    bf16* op = (bf16*)outp;
                    op[ob + 0] = __float2bfloat16(r0);
                    op[ob + 1] = __float2bfloat16(r1);
                    op[ob + 2] = __float2bfloat16(r2);
                    op[ob + 3] = __float2bfloat16(r3);
                }
            }
        }
    }
}

// ---------------------------------------------------------------------------
extern "C" void kernel_launch(void* const* d_in, const int* in_sizes, int n_in,
                              void* d_out, int out_size, void* d_ws, size_t ws_size,
                              hipStream_t stream) {
    const void* x     = d_in[0];
    const void* A     = d_in[1];
    const void* PA    = d_in[2];
    const void* wA    = d_in[3];
    const void* Wa    = d_in[4];
    const void* ba    = d_in[5];
    const void* Wb    = d_in[6];
    const void* bb    = d_in[7];
    const void* Wd    = d_in[8];
    const void* bd    = d_in[9];
    const void* gamma = d_in[10];
    const void* beta  = d_in[11];

    int*   flagp  = (int*)d_ws;
    float* wsf    = (float*)d_ws;
    float* A_comb = wsf + 64;
    float* S1     = wsf + 64 + 2048;   // reused in-place as A1

    hipMemsetAsync(S1, 0, (size_t)S * NN * V * V * sizeof(float), stream);
    k_detect<<<1, 64, 0, stream>>>(x, flagp);
    k_acomb<<<1, 128, 0, stream>>>(A, PA, wA, A_comb, flagp);
    k_s1<<<dim3(TT / TCH, NN, S), 256, 0, stream>>>(x, Wa, ba, Wb, bb, S1, flagp);
    k_a1<<<S * NN, 64, 0, stream>>>(S1);
    k_main<<<NN * TT / TB, 256, 0, stream>>>(x, Wa, ba, Wb, bb, Wd, bd, gamma, beta, wA,
                                             A_comb, S1, d_out, flagp);
}

// Round 5
// 389.440 us; speedup vs baseline: 2.4700x; 1.4111x over previous
//
#include <hip/hip_runtime.h>
#include <hip/hip_bf16.h>

typedef __hip_bfloat16 bf16;
typedef __attribute__((ext_vector_type(8))) short short8;
typedef __attribute__((ext_vector_type(4))) float f32x4;

#define S  3
#define V  25
#define C  64
#define O  64
#define IC 16
#define NN 32
#define TT 256
#define TB 2
#define TCH 32

__device__ __forceinline__ float b2f(bf16 v) { return __bfloat162float(v); }

__device__ __forceinline__ float ldv(const void* p, size_t i, int f32) {
    return f32 ? ((const float*)p)[i] : b2f(((const bf16*)p)[i]);
}

__device__ __forceinline__ unsigned short f2bf(float f) {
    bf16 h = __float2bfloat16(f);
    return *(unsigned short*)&h;
}

__device__ __forceinline__ void fma4(float4& a, float s, float4 b) {
    a.x += s * b.x; a.y += s * b.y; a.z += s * b.z; a.w += s * b.w;
}

__device__ __forceinline__ float dot16v(const float* a, const float* b) {
    float4 a0 = *(const float4*)(a + 0),  a1 = *(const float4*)(a + 4);
    float4 a2 = *(const float4*)(a + 8),  a3 = *(const float4*)(a + 12);
    float4 b0 = *(const float4*)(b + 0),  b1 = *(const float4*)(b + 4);
    float4 b2 = *(const float4*)(b + 8),  b3 = *(const float4*)(b + 12);
    float e = a0.x*b0.x + a0.y*b0.y + a0.z*b0.z + a0.w*b0.w;
    e += a1.x*b1.x + a1.y*b1.y + a1.z*b1.z + a1.w*b1.w;
    e += a2.x*b2.x + a2.y*b2.y + a2.z*b2.z + a2.w*b2.w;
    e += a3.x*b3.x + a3.y*b3.y + a3.z*b3.z + a3.w*b3.w;
    return e;
}

// ---------------------------------------------------------------------------
__global__ void k_detect(const void* __restrict__ x, int* __restrict__ flag) {
    if (threadIdx.x == 0) {
        const bf16* p = (const bf16*)x;
        int f32 = 0;
        for (int i = 0; i < 2048; i++) {
            float v = b2f(p[i]);
            if (!(v > -1000.f && v < 1000.f)) { f32 = 1; break; }
        }
        *flag = f32;
    }
}

// ---------------------------------------------------------------------------
__global__ void k_acomb(const void* __restrict__ A, const void* __restrict__ PA,
                        const void* __restrict__ wA, float* __restrict__ A_comb,
                        const int* __restrict__ flagp) {
    int f32 = *flagp;
    int r = threadIdx.x;
    if (r >= S * V) return;
    float w0 = ldv(wA, 0, f32), w1 = ldv(wA, 1, f32);
    float vals[V];
    float m = -1e30f;
    for (int v = 0; v < V; v++) { vals[v] = ldv(PA, r * V + v, f32); m = fmaxf(m, vals[v]); }
    float sum = 0.f;
    for (int v = 0; v < V; v++) { vals[v] = __expf(vals[v] - m); sum += vals[v]; }
    float inv = 1.f / sum;
    float* outp = A_comb + r * V;
    for (int v = 0; v < V; v++) outp[v] = w0 * ldv(A, r * V + v, f32) + w1 * vals[v] * inv;
}

// ---------------------------------------------------------------------------
// k_s1: unchanged from round 4 (fast)
// ---------------------------------------------------------------------------
__global__ __launch_bounds__(256) void k_s1(
    const void* __restrict__ x,
    const void* __restrict__ Wa, const void* __restrict__ ba,
    const void* __restrict__ Wb, const void* __restrict__ bb,
    float* __restrict__ S1g, const int* __restrict__ flagp) {
    int f32 = *flagp;
    int tchunk = blockIdx.x, n = blockIdx.y, s = blockIdx.z;
    int tid = threadIdx.x;

    __shared__ __align__(16) float xs[2][V][68];
    __shared__ __align__(16) float was[C][IC], wbs[C][IC];
    __shared__ __align__(16) float qa[2][V][20], kb[2][V][20];
    __shared__ __align__(16) float bas[IC], bbs[IC];

    if (f32) {
        const float4* Wa4 = (const float4*)Wa + s * 256;
        const float4* Wb4 = (const float4*)Wb + s * 256;
        if (tid < 256) { ((float4*)was)[tid] = Wa4[tid]; ((float4*)wbs)[tid] = Wb4[tid]; }
    } else {
        for (int w = tid; w < 1024; w += 256) {
            ((float*)was)[w] = ldv(Wa, (size_t)s * 1024 + w, 0);
            ((float*)wbs)[w] = ldv(Wb, (size_t)s * 1024 + w, 0);
        }
    }
    if (tid < IC) { bas[tid] = ldv(ba, s * IC + tid, f32); bbs[tid] = ldv(bb, s * IC + tid, f32); }

    float acc[2][2] = {{0.f, 0.f}, {0.f, 0.f}};
    int t0 = tchunk * TCH;
    for (int tt = 0; tt < TCH; tt += 2) {
        __syncthreads();
        if (f32) {
            const float4* xp = (const float4*)x + (size_t)(n * TT + t0 + tt) * 400;
            for (int w = tid; w < 800; w += 256) {
                int t = w / 400, r = w % 400;
                *(float4*)&xs[t][r >> 4][(r & 15) * 4] = xp[w];
            }
        } else {
            size_t base = (size_t)(n * TT + t0 + tt) * V * C;
            for (int w = tid; w < 3200; w += 256)
                xs[w / 1600][(w % 1600) >> 6][w & 63] = ldv(x, base + w, 0);
        }
        __syncthreads();
        if (tid < 100) {
            int u = tid >> 2, iq = tid & 3;
            float4 bq = *(const float4*)&bas[iq * 4];
            float4 bk = *(const float4*)&bbs[iq * 4];
            float4 aq0 = bq, aq1 = bq, ak0 = bk, ak1 = bk;
            #pragma unroll
            for (int c4 = 0; c4 < 16; c4++) {
                float4 xv0 = *(const float4*)&xs[0][u][c4 * 4];
                float4 xv1 = *(const float4*)&xs[1][u][c4 * 4];
                float x0a[4], x1a[4];
                *(float4*)x0a = xv0; *(float4*)x1a = xv1;
                #pragma unroll
                for (int k = 0; k < 4; k++) {
                    float4 wav = *(const float4*)&was[c4 * 4 + k][iq * 4];
                    float4 wbv = *(const float4*)&wbs[c4 * 4 + k][iq * 4];
                    fma4(aq0, x0a[k], wav); fma4(aq1, x1a[k], wav);
                    fma4(ak0, x0a[k], wbv); fma4(ak1, x1a[k], wbv);
                }
            }
            *(float4*)&qa[0][u][iq * 4] = aq0;
            *(float4*)&qa[1][u][iq * 4] = aq1;
            *(float4*)&kb[0][u][iq * 4] = ak0;
            *(float4*)&kb[1][u][iq * 4] = ak1;
        }
        __syncthreads();
        #pragma unroll
        for (int j = 0; j < 2; j++) {
            int w = tid + j * 256;
            if (w < 325) {
                int u = w / 13, v = (w % 13) * 2;
                #pragma unroll
                for (int t = 0; t < 2; t++) {
                    acc[j][0] += dot16v(qa[t][u], kb[t][v]);
                    if (v + 1 < V) acc[j][1] += dot16v(qa[t][u], kb[t][v + 1]);
                }
            }
        }
    }
    #pragma unroll
    for (int j = 0; j < 2; j++) {
        int w = tid + j * 256;
        if (w < 325) {
            int u = w / 13, v = (w % 13) * 2;
            size_t base = (size_t)(s * NN + n) * 625 + u * 25 + v;
            atomicAdd(&S1g[base], acc[j][0]);
            if (v + 1 < V) atomicAdd(&S1g[base + 1], acc[j][1]);
        }
    }
}

// ---------------------------------------------------------------------------
__global__ void k_a1(float* __restrict__ S1g) {
    int sn = blockIdx.x;
    int u = threadIdx.x;
    if (u >= V) return;
    float* row = S1g + (size_t)sn * V * V + u * V;
    const float scale = 1.0f / 64.0f;
    float vals[V];
    float m = -1e30f;
    for (int v = 0; v < V; v++) { vals[v] = row[v] * scale; m = fmaxf(m, vals[v]); }
    float sum = 0.f;
    for (int v = 0; v < V; v++) { vals[v] = __expf(vals[v] - m); sum += vals[v]; }
    float inv = 1.f / sum;
    for (int v = 0; v < V; v++) row[v] = vals[v] * inv;
}

// ---------------------------------------------------------------------------
// k_main: proj(VALU) -> E+exp(VALU) -> softmax/combine -> z=Ain·x (VALU, bf16
// out) -> y += z·Wd via MFMA bf16 (acc in VGPRs across s) -> epilogue
// ---------------------------------------------------------------------------
__global__ __launch_bounds__(256, 3) void k_main(
    const void* __restrict__ x,
    const void* __restrict__ Wa, const void* __restrict__ ba,
    const void* __restrict__ Wb, const void* __restrict__ bb,
    const void* __restrict__ Wd, const void* __restrict__ bd,
    const void* __restrict__ gamma, const void* __restrict__ beta,
    const void* __restrict__ wA,
    const float* __restrict__ A_comb, const float* __restrict__ A1g,
    void* __restrict__ outp, const int* __restrict__ flagp) {
    int f32 = *flagp;
    int bx = blockIdx.x;
    int n = bx >> 7, tc = bx & 127;
    int t0 = tc * TB;
    int tid = threadIdx.x;

    __shared__ __align__(16) float xs[TB][V][68];            // 13600 B
    __shared__ __align__(16) float was[C][IC];               //  4096 B
    __shared__ __align__(16) float wbs[C][IC];               //  4096 B
    __shared__ __align__(16) unsigned short wdt[O * 72];     //  9216 B (WdT bf16, [o][c] pad72)
    __shared__ __align__(16) char poolc[9216];               //  qa/kb f32 OR zb bf16[64][72]
    __shared__ float Ain[TB][V][26];                          //  5200 B
    __shared__ float ac1[V][26];                              //  2600 B
    __shared__ float sinv[TB][V];
    __shared__ __align__(16) float bas[IC], bbs[IC];
    __shared__ float gs[O], bts[O], bds[O];

    float* pool = (float*)poolc;                  // qa[t]:t*500+u*20  kb: +1000
    unsigned short* zb = (unsigned short*)poolc;  // zb[row*72 + c], row = t*25+u

    if (f32) {
        const float4* xp = (const float4*)x + (size_t)(n * TT + t0) * 400;
        for (int w = tid; w < 800; w += 256) {
            int t = w / 400, r = w % 400;
            *(float4*)&xs[t][r >> 4][(r & 15) * 4] = xp[w];
        }
    } else {
        size_t base = (size_t)(n * TT + t0) * V * C;
        for (int w = tid; w < 3200; w += 256)
            xs[w / 1600][(w % 1600) >> 6][w & 63] = ldv(x, base + w, 0);
    }
    if (tid < O) {
        bds[tid] = ldv(bd, tid, f32) + ldv(bd, O + tid, f32) + ldv(bd, 2 * O + tid, f32);
        gs[tid] = ldv(gamma, tid, f32) * rsqrtf(1.f + 1e-5f);
        bts[tid] = ldv(beta, tid, f32);
    }
    float w2 = ldv(wA, 2, f32), w3 = ldv(wA, 3, f32);

    f32x4 acc[4];
    #pragma unroll
    for (int nt = 0; nt < 4; nt++) acc[nt] = (f32x4){0.f, 0.f, 0.f, 0.f};

    for (int s = 0; s < S; s++) {
        __syncthreads();   // prev-s MFMA readers of zb/wdt done
        if (f32) {
            const float4* Wa4 = (const float4*)Wa + s * 256;
            const float4* Wb4 = (const float4*)Wb + s * 256;
            if (tid < 256) { ((float4*)was)[tid] = Wa4[tid]; ((float4*)wbs)[tid] = Wb4[tid]; }
            const float4* Wd4 = (const float4*)Wd + s * 1024;
            for (int j = tid; j < 1024; j += 256) {
                int c = j >> 4, o0 = (j & 15) * 4;
                float4 v = Wd4[j];
                wdt[(o0 + 0) * 72 + c] = f2bf(v.x);
                wdt[(o0 + 1) * 72 + c] = f2bf(v.y);
                wdt[(o0 + 2) * 72 + c] = f2bf(v.z);
                wdt[(o0 + 3) * 72 + c] = f2bf(v.w);
            }
        } else {
            for (int w = tid; w < 1024; w += 256) {
                ((float*)was)[w] = ldv(Wa, (size_t)s * 1024 + w, 0);
                ((float*)wbs)[w] = ldv(Wb, (size_t)s * 1024 + w, 0);
            }
            for (int w = tid; w < 4096; w += 256) {
                int c = w >> 6, o = w & 63;
                wdt[o * 72 + c] = f2bf(ldv(Wd, (size_t)s * 4096 + w, 0));
            }
        }
        if (tid < IC) { bas[tid] = ldv(ba, s * IC + tid, f32); bbs[tid] = ldv(bb, s * IC + tid, f32); }
        {
            const float* acp = A_comb + (size_t)s * 625;
            const float* a1p = A1g + (size_t)(s * NN + n) * 625;
            for (int w = tid; w < 625; w += 256)
                ac1[w / 25][w % 25] = acp[w] + w2 * a1p[w];
        }
        __syncthreads();

        // proj: 200 tasks (sel, u, iq), each 2t x 4i
        if (tid < 200) {
            int sel = tid >= 100;
            int rr = tid - sel * 100;
            int u = rr >> 2, iq = rr & 3;
            const float(*W)[IC] = sel ? wbs : was;
            float4 bias = *(const float4*)&(sel ? bbs : bas)[iq * 4];
            float4 a0 = bias, a1 = bias;
            #pragma unroll
            for (int c4 = 0; c4 < 16; c4++) {
                float4 xv0 = *(const float4*)&xs[0][u][c4 * 4];
                float4 xv1 = *(const float4*)&xs[1][u][c4 * 4];
                float x0a[4], x1a[4];
                *(float4*)x0a = xv0; *(float4*)x1a = xv1;
                #pragma unroll
                for (int k = 0; k < 4; k++) {
                    float4 wv = *(const float4*)&W[c4 * 4 + k][iq * 4];
                    fma4(a0, x0a[k], wv); fma4(a1, x1a[k], wv);
                }
            }
            int base = sel * 1000;
            *(float4*)&pool[base + u * 20 + iq * 4] = a0;
            *(float4*)&pool[base + 500 + u * 20 + iq * 4] = a1;
        }
        __syncthreads();

        // E + exp: 650 tasks (t, u, v-pair)
        for (int w = tid; w < 650; w += 256) {
            int t = w / 325, r = w % 325, u = r / 13, v = (r % 13) * 2;
            const float* qr = &pool[t * 500 + u * 20];
            const float* k0 = &pool[1000 + t * 500 + v * 20];
            Ain[t][u][v] = __expf(dot16v(qr, k0) * 0.25f);
            if (v + 1 < V) Ain[t][u][v + 1] = __expf(dot16v(qr, k0 + 20) * 0.25f);
        }
        __syncthreads();

        if (tid < TB * V) {
            int t = tid / V, u = tid % V;
            float sm = 0.f;
            for (int v = 0; v < V; v++) sm += Ain[t][u][v];
            sinv[t][u] = w3 / sm;
        }
        __syncthreads();

        for (int w = tid; w < 1250; w += 256) {
            int t = w / 625, r = w % 625, u = r / 25, v = r % 25;
            Ain[t][u][v] = ac1[u][v] + sinv[t][u] * Ain[t][u][v];
        }
        __syncthreads();   // also: E readers of pool done before zb overwrite

        // z[t][u][c] = sum_v Ain·x  -> bf16 zb rows (overwrites dead qa/kb)
        for (int w = tid; w < 800; w += 256) {
            int t = w / 400, r = w % 400, u = r >> 4, c4 = r & 15;
            float4 a = make_float4(0.f, 0.f, 0.f, 0.f);
            const float* arow = Ain[t][u];
            #pragma unroll
            for (int v = 0; v < V; v++)
                fma4(a, arow[v], *(const float4*)&xs[t][v][c4 * 4]);
            unsigned short hz[4] = {f2bf(a.x), f2bf(a.y), f2bf(a.z), f2bf(a.w)};
            *(uint2*)&zb[(t * 25 + u) * 72 + c4 * 4] = *(uint2*)hz;
        }
        __syncthreads();

        // y += z·Wd via MFMA: wave w owns rows 16w..16w+15; 4 N-tiles, K=64
        {
            int lane = tid & 63, wv = tid >> 6;
            int arow = wv * 16 + (lane & 15);
            int kq = lane >> 4;
            short8 a0 = *(const short8*)&zb[arow * 72 + kq * 8];
            short8 a1 = *(const short8*)&zb[arow * 72 + 32 + kq * 8];
            #pragma unroll
            for (int nt = 0; nt < 4; nt++) {
                int brow = nt * 16 + (lane & 15);
                short8 b0 = *(const short8*)&wdt[brow * 72 + kq * 8];
                short8 b1 = *(const short8*)&wdt[brow * 72 + 32 + kq * 8];
                acc[nt] = __builtin_amdgcn_mfma_f32_16x16x32_bf16(a0, b0, acc[nt], 0, 0, 0);
                acc[nt] = __builtin_amdgcn_mfma_f32_16x16x32_bf16(a1, b1, acc[nt], 0, 0, 0);
            }
        }
        // loop-top barrier protects zb/wdt until MFMA of all waves done
    }

    // epilogue from MFMA C/D layout: col=lane&15, row=(lane>>4)*4+reg
    {
        int lane = tid & 63, wv = tid >> 6;
        int rb = wv * 16 + ((lane >> 4) << 2);
        int col = lane & 15;
        #pragma unroll
        for (int nt = 0; nt < 4; nt++) {
            int o = nt * 16 + col;
            float g = gs[o], bt_ = bts[o], bsum = bds[o];
            float av[4];
            *(f32x4*)av = acc[nt];
            #pragma unroll
            for (int j = 0; j < 4; j++) {
                int rg = rb + j;
                if (rg < TB * V) {
                    int t = rg / V, u = rg % V;
                    float yv = fmaxf((av[j] + bsum) * g + bt_ + xs[t][u][o], 0.f);
                    size_t ob = (size_t)((n * TT + t0 + t) * V + u) * O + o;
                    if (f32) ((float*)outp)[ob] = yv;
                    else     ((bf16*)outp)[ob] = __float2bfloat16(yv);
                }
            }
        }
    }
}

// ---------------------------------------------------------------------------
extern "C" void kernel_launch(void* const* d_in, const int* in_sizes, int n_in,
                              void* d_out, int out_size, void* d_ws, size_t ws_size,
                              hipStream_t stream) {
    const void* x     = d_in[0];
    const void* A     = d_in[1];
    const void* PA    = d_in[2];
    const void* wA    = d_in[3];
    const void* Wa    = d_in[4];
    const void* ba    = d_in[5];
    const void* Wb    = d_in[6];
    const void* bb    = d_in[7];
    const void* Wd    = d_in[8];
    const void* bd    = d_in[9];
    const void* gamma = d_in[10];
    const void* beta  = d_in[11];

    int*   flagp  = (int*)d_ws;
    float* wsf    = (float*)d_ws;
    float* A_comb = wsf + 64;
    float* S1     = wsf + 64 + 2048;   // reused in-place as A1

    hipMemsetAsync(S1, 0, (size_t)S * NN * V * V * sizeof(float), stream);
    k_detect<<<1, 64, 0, stream>>>(x, flagp);
    k_acomb<<<1, 128, 0, stream>>>(A, PA, wA, A_comb, flagp);
    k_s1<<<dim3(TT / TCH, NN, S), 256, 0, stream>>>(x, Wa, ba, Wb, bb, S1, flagp);
    k_a1<<<S * NN, 64, 0, stream>>>(S1);
    k_main<<<NN * TT / TB, 256, 0, stream>>>(x, Wa, ba, Wb, bb, Wd, bd, gamma, beta, wA,
                                             A_comb, S1, d_out, flagp);
}

// Round 6
// 352.737 us; speedup vs baseline: 2.7271x; 1.1041x over previous
//
#include <hip/hip_runtime.h>
#include <hip/hip_bf16.h>

typedef __hip_bfloat16 bf16;
typedef __attribute__((ext_vector_type(8))) short short8;
typedef __attribute__((ext_vector_type(4))) float f32x4;

#define S  3
#define V  25
#define C  64
#define O  64
#define IC 16
#define NN 32
#define TT 256
#define TB 2
#define TCH 32

__device__ __forceinline__ float b2f(bf16 v) { return __bfloat162float(v); }

__device__ __forceinline__ float ldv(const void* p, size_t i, int f32) {
    return f32 ? ((const float*)p)[i] : b2f(((const bf16*)p)[i]);
}

__device__ __forceinline__ unsigned short f2bf(float f) {
    bf16 h = __float2bfloat16(f);
    return *(unsigned short*)&h;
}

__device__ __forceinline__ void fma4(float4& a, float s, float4 b) {
    a.x += s * b.x; a.y += s * b.y; a.z += s * b.z; a.w += s * b.w;
}

__device__ __forceinline__ float dot16v(const float* a, const float* b) {
    float4 a0 = *(const float4*)(a + 0),  a1 = *(const float4*)(a + 4);
    float4 a2 = *(const float4*)(a + 8),  a3 = *(const float4*)(a + 12);
    float4 b0 = *(const float4*)(b + 0),  b1 = *(const float4*)(b + 4);
    float4 b2 = *(const float4*)(b + 8),  b3 = *(const float4*)(b + 12);
    float e = a0.x*b0.x + a0.y*b0.y + a0.z*b0.z + a0.w*b0.w;
    e += a1.x*b1.x + a1.y*b1.y + a1.z*b1.z + a1.w*b1.w;
    e += a2.x*b2.x + a2.y*b2.y + a2.z*b2.z + a2.w*b2.w;
    e += a3.x*b3.x + a3.y*b3.y + a3.z*b3.z + a3.w*b3.w;
    return e;
}

// ---------------------------------------------------------------------------
__global__ void k_detect(const void* __restrict__ x, int* __restrict__ flag) {
    if (threadIdx.x == 0) {
        const bf16* p = (const bf16*)x;
        int f32 = 0;
        for (int i = 0; i < 2048; i++) {
            float v = b2f(p[i]);
            if (!(v > -1000.f && v < 1000.f)) { f32 = 1; break; }
        }
        *flag = f32;
    }
}

// ---------------------------------------------------------------------------
__global__ void k_acomb(const void* __restrict__ A, const void* __restrict__ PA,
                        const void* __restrict__ wA, float* __restrict__ A_comb,
                        const int* __restrict__ flagp) {
    int f32 = *flagp;
    int r = threadIdx.x;
    if (r >= S * V) return;
    float w0 = ldv(wA, 0, f32), w1 = ldv(wA, 1, f32);
    float vals[V];
    float m = -1e30f;
    for (int v = 0; v < V; v++) { vals[v] = ldv(PA, r * V + v, f32); m = fmaxf(m, vals[v]); }
    float sum = 0.f;
    for (int v = 0; v < V; v++) { vals[v] = __expf(vals[v] - m); sum += vals[v]; }
    float inv = 1.f / sum;
    float* outp = A_comb + r * V;
    for (int v = 0; v < V; v++) outp[v] = w0 * ldv(A, r * V + v, f32) + w1 * vals[v] * inv;
}

// ---------------------------------------------------------------------------
// k_s1: unchanged (known-good)
// ---------------------------------------------------------------------------
__global__ __launch_bounds__(256) void k_s1(
    const void* __restrict__ x,
    const void* __restrict__ Wa, const void* __restrict__ ba,
    const void* __restrict__ Wb, const void* __restrict__ bb,
    float* __restrict__ S1g, const int* __restrict__ flagp) {
    int f32 = *flagp;
    int tchunk = blockIdx.x, n = blockIdx.y, s = blockIdx.z;
    int tid = threadIdx.x;

    __shared__ __align__(16) float xs[2][V][68];
    __shared__ __align__(16) float was[C][IC], wbs[C][IC];
    __shared__ __align__(16) float qa[2][V][20], kb[2][V][20];
    __shared__ __align__(16) float bas[IC], bbs[IC];

    if (f32) {
        const float4* Wa4 = (const float4*)Wa + s * 256;
        const float4* Wb4 = (const float4*)Wb + s * 256;
        if (tid < 256) { ((float4*)was)[tid] = Wa4[tid]; ((float4*)wbs)[tid] = Wb4[tid]; }
    } else {
        for (int w = tid; w < 1024; w += 256) {
            ((float*)was)[w] = ldv(Wa, (size_t)s * 1024 + w, 0);
            ((float*)wbs)[w] = ldv(Wb, (size_t)s * 1024 + w, 0);
        }
    }
    if (tid < IC) { bas[tid] = ldv(ba, s * IC + tid, f32); bbs[tid] = ldv(bb, s * IC + tid, f32); }

    float acc[2][2] = {{0.f, 0.f}, {0.f, 0.f}};
    int t0 = tchunk * TCH;
    for (int tt = 0; tt < TCH; tt += 2) {
        __syncthreads();
        if (f32) {
            const float4* xp = (const float4*)x + (size_t)(n * TT + t0 + tt) * 400;
            for (int w = tid; w < 800; w += 256) {
                int t = w / 400, r = w % 400;
                *(float4*)&xs[t][r >> 4][(r & 15) * 4] = xp[w];
            }
        } else {
            size_t base = (size_t)(n * TT + t0 + tt) * V * C;
            for (int w = tid; w < 3200; w += 256)
                xs[w / 1600][(w % 1600) >> 6][w & 63] = ldv(x, base + w, 0);
        }
        __syncthreads();
        if (tid < 100) {
            int u = tid >> 2, iq = tid & 3;
            float4 bq = *(const float4*)&bas[iq * 4];
            float4 bk = *(const float4*)&bbs[iq * 4];
            float4 aq0 = bq, aq1 = bq, ak0 = bk, ak1 = bk;
            #pragma unroll
            for (int c4 = 0; c4 < 16; c4++) {
                float4 xv0 = *(const float4*)&xs[0][u][c4 * 4];
                float4 xv1 = *(const float4*)&xs[1][u][c4 * 4];
                float x0a[4], x1a[4];
                *(float4*)x0a = xv0; *(float4*)x1a = xv1;
                #pragma unroll
                for (int k = 0; k < 4; k++) {
                    float4 wav = *(const float4*)&was[c4 * 4 + k][iq * 4];
                    float4 wbv = *(const float4*)&wbs[c4 * 4 + k][iq * 4];
                    fma4(aq0, x0a[k], wav); fma4(aq1, x1a[k], wav);
                    fma4(ak0, x0a[k], wbv); fma4(ak1, x1a[k], wbv);
                }
            }
            *(float4*)&qa[0][u][iq * 4] = aq0;
            *(float4*)&qa[1][u][iq * 4] = aq1;
            *(float4*)&kb[0][u][iq * 4] = ak0;
            *(float4*)&kb[1][u][iq * 4] = ak1;
        }
        __syncthreads();
        #pragma unroll
        for (int j = 0; j < 2; j++) {
            int w = tid + j * 256;
            if (w < 325) {
                int u = w / 13, v = (w % 13) * 2;
                #pragma unroll
                for (int t = 0; t < 2; t++) {
                    acc[j][0] += dot16v(qa[t][u], kb[t][v]);
                    if (v + 1 < V) acc[j][1] += dot16v(qa[t][u], kb[t][v + 1]);
                }
            }
        }
    }
    #pragma unroll
    for (int j = 0; j < 2; j++) {
        int w = tid + j * 256;
        if (w < 325) {
            int u = w / 13, v = (w % 13) * 2;
            size_t base = (size_t)(s * NN + n) * 625 + u * 25 + v;
            atomicAdd(&S1g[base], acc[j][0]);
            if (v + 1 < V) atomicAdd(&S1g[base + 1], acc[j][1]);
        }
    }
}

// ---------------------------------------------------------------------------
__global__ void k_a1(float* __restrict__ S1g) {
    int sn = blockIdx.x;
    int u = threadIdx.x;
    if (u >= V) return;
    float* row = S1g + (size_t)sn * V * V + u * V;
    const float scale = 1.0f / 64.0f;
    float vals[V];
    float m = -1e30f;
    for (int v = 0; v < V; v++) { vals[v] = row[v] * scale; m = fmaxf(m, vals[v]); }
    float sum = 0.f;
    for (int v = 0; v < V; v++) { vals[v] = __expf(vals[v] - m); sum += vals[v]; }
    float inv = 1.f / sum;
    for (int v = 0; v < V; v++) row[v] = vals[v] * inv;
}

// ---------------------------------------------------------------------------
// k_main (full-MFMA): row space m = t*32+u (64 rows, waves 0,1->t0 2,3->t1).
// Per s: P1 qa/kb = xb*W (MFMA) -> qab/kbb; P3 xw = xb*Wd (MFMA) -> xwtb^T;
// P2 E = qab*kbb^T (MFMA) -> exp/rowsum(shfl)/combine -> Ainb;
// P4 y += Ainb*xwtb (MFMA, VGPR acc over s). Epilogue: BN+residual+relu.
// MFMA operand conventions verified by round-5 passing kernel:
//   A-frag: st[m][k], lane m=lane&15, koff=(lane>>4)*8 (short8)
//   B-frag: st[n][k], lane n=lane&15, same koff
//   C/D   : col=lane&15 (+16*nt), row=(lane>>4)*4+reg (+16*wave)
// ---------------------------------------------------------------------------
__global__ __launch_bounds__(256, 3) void k_main(
    const void* __restrict__ x,
    const void* __restrict__ Wa, const void* __restrict__ ba,
    const void* __restrict__ Wb, const void* __restrict__ bb,
    const void* __restrict__ Wd, const void* __restrict__ bd,
    const void* __restrict__ gamma, const void* __restrict__ beta,
    const void* __restrict__ wA,
    const float* __restrict__ A_comb, const float* __restrict__ A1g,
    void* __restrict__ outp, const int* __restrict__ flagp) {
    int f32 = *flagp;
    int bx = blockIdx.x;
    int n = bx >> 7, tc = bx & 127;
    int t0 = tc * TB;
    int tid = threadIdx.x;
    int lane = tid & 63, wv = tid >> 6;
    int lm = lane & 15, kq = lane >> 4;

    __shared__ __align__(16) unsigned short xb[64 * 72];     // 9216 B  x bf16, rows t*32+u
    __shared__ __align__(16) unsigned short watb[16 * 72];   // 2304 B  Wa^T [i][c]
    __shared__ __align__(16) unsigned short wbtb[16 * 72];   // 2304 B  Wb^T [i][c]
    __shared__ __align__(16) unsigned short wdtb[64 * 72];   // 9216 B  Wd^T [o][c]
    __shared__ __align__(16) unsigned short qab[64 * 40];    // 5120 B  qa [m][i] pad k
    __shared__ __align__(16) unsigned short kbb[64 * 40];    // 5120 B  kb [m][i]
    __shared__ __align__(16) unsigned short Ainb[64 * 40];   // 5120 B  Ain [m][v]
    __shared__ __align__(16) unsigned short xwtb[2 * 64 * 40]; // 10240 B xw^T [t][o][v]
    __shared__ float ac1[V][26];                             // 2600 B
    __shared__ float gs[O], bts[O], bds[O];                  // 768 B

    // ---- once per block: stage xb (zero-padded), zero qab/kbb k-pad, epilogue consts
    for (int w = tid; w < 64 * 36; w += 256) {
        int r = w / 36, cq = w % 36;
        int t = r >> 5, u = r & 31;
        int c = cq * 2;
        unsigned int pk = 0;
        if (u < V && c < C) {
            size_t base = (size_t)((n * TT + t0 + t) * V + u) * C + c;
            unsigned int h0 = f2bf(ldv(x, base, f32));
            unsigned int h1 = f2bf(ldv(x, base + 1, f32));
            pk = h0 | (h1 << 16);
        }
        ((unsigned int*)xb)[r * 36 + cq] = pk;
    }
    for (int w = tid; w < 512; w += 256) {   // zero cols 16..31 (words 8..15) once
        int r = w >> 3, cw = 8 + (w & 7);
        ((unsigned int*)qab)[r * 20 + cw] = 0;
        ((unsigned int*)kbb)[r * 20 + cw] = 0;
    }
    if (tid < O) {
        bds[tid] = ldv(bd, tid, f32) + ldv(bd, O + tid, f32) + ldv(bd, 2 * O + tid, f32);
        gs[tid] = ldv(gamma, tid, f32) * rsqrtf(1.f + 1e-5f);
        bts[tid] = ldv(beta, tid, f32);
    }
    float w2 = ldv(wA, 2, f32), w3 = ldv(wA, 3, f32);

    f32x4 acc[4];
    #pragma unroll
    for (int nt = 0; nt < 4; nt++) acc[nt] = (f32x4){0.f, 0.f, 0.f, 0.f};

    int t_ = wv >> 1;                 // this wave's timestep
    int mrow = wv * 16 + lm;          // A-frag row
    int drow0 = wv * 16 + (kq << 2);  // C/D row base (+reg)
    int ub = ((wv & 1) << 4) + (kq << 2);  // u base for D rows

    for (int s = 0; s < S; s++) {
        // ---- staging (safe vs prev-iter readers: all their reads precede sync4(s-1))
        for (int w = tid; w < 1024; w += 256) {
            watb[(w & 15) * 72 + (w >> 4)] = f2bf(ldv(Wa, (size_t)s * 1024 + w, f32));
            wbtb[(w & 15) * 72 + (w >> 4)] = f2bf(ldv(Wb, (size_t)s * 1024 + w, f32));
        }
        for (int w = tid; w < 4096; w += 256) {
            int c = w >> 6, o = w & 63;
            wdtb[o * 72 + c] = f2bf(ldv(Wd, (size_t)s * 4096 + w, f32));
        }
        {
            const float* acp = A_comb + (size_t)s * 625;
            const float* a1p = A1g + (size_t)(s * NN + n) * 625;
            for (int w = tid; w < 625; w += 256)
                ac1[w / 25][w % 25] = acp[w] + w2 * a1p[w];
        }
        float biq = ldv(ba, s * IC + lm, f32);
        float bik = ldv(bb, s * IC + lm, f32);
        __syncthreads();   // sync2: staging + (s>0) P4 readers of xwtb/Ainb

        // ---- P1: qa/kb MFMA  (+ P3 shares A-frags)
        short8 xa0 = *(const short8*)&xb[mrow * 72 + kq * 8];
        short8 xa1 = *(const short8*)&xb[mrow * 72 + 32 + kq * 8];
        {
            short8 wa0 = *(const short8*)&watb[lm * 72 + kq * 8];
            short8 wa1 = *(const short8*)&watb[lm * 72 + 32 + kq * 8];
            short8 wb0 = *(const short8*)&wbtb[lm * 72 + kq * 8];
            short8 wb1 = *(const short8*)&wbtb[lm * 72 + 32 + kq * 8];
            f32x4 q = __builtin_amdgcn_mfma_f32_16x16x32_bf16(xa0, wa0, (f32x4){0.f,0.f,0.f,0.f}, 0, 0, 0);
            q = __builtin_amdgcn_mfma_f32_16x16x32_bf16(xa1, wa1, q, 0, 0, 0);
            f32x4 k = __builtin_amdgcn_mfma_f32_16x16x32_bf16(xa0, wb0, (f32x4){0.f,0.f,0.f,0.f}, 0, 0, 0);
            k = __builtin_amdgcn_mfma_f32_16x16x32_bf16(xa1, wb1, k, 0, 0, 0);
            #pragma unroll
            for (int reg = 0; reg < 4; reg++) {
                qab[(drow0 + reg) * 40 + lm] = f2bf(q[reg] + biq);
                kbb[(drow0 + reg) * 40 + lm] = f2bf(k[reg] + bik);
            }
        }
        // ---- P3: xw = xb * Wd -> xwtb transposed [t][o][v]
        {
            #pragma unroll
            for (int nt = 0; nt < 4; nt++) {
                short8 wd0 = *(const short8*)&wdtb[(nt * 16 + lm) * 72 + kq * 8];
                short8 wd1 = *(const short8*)&wdtb[(nt * 16 + lm) * 72 + 32 + kq * 8];
                f32x4 xw = __builtin_amdgcn_mfma_f32_16x16x32_bf16(xa0, wd0, (f32x4){0.f,0.f,0.f,0.f}, 0, 0, 0);
                xw = __builtin_amdgcn_mfma_f32_16x16x32_bf16(xa1, wd1, xw, 0, 0, 0);
                unsigned short h[4] = {f2bf(xw[0]), f2bf(xw[1]), f2bf(xw[2]), f2bf(xw[3])};
                // D rows = t*32 + v (v = ub+reg), cols o = nt*16+lm; write [o][v]
                *(uint2*)&xwtb[t_ * 2560 + (nt * 16 + lm) * 40 + ub] = *(uint2*)h;
            }
        }
        __syncthreads();   // sync3: qab/kbb/xwtb written

        // ---- P2: E MFMA -> exp -> rowsum(shfl) -> combine -> Ainb
        {
            short8 aq = *(const short8*)&qab[mrow * 40 + kq * 8];
            short8 bk0 = *(const short8*)&kbb[(t_ * 32 + lm) * 40 + kq * 8];
            short8 bk1 = *(const short8*)&kbb[(t_ * 32 + 16 + lm) * 40 + kq * 8];
            f32x4 e0 = __builtin_amdgcn_mfma_f32_16x16x32_bf16(aq, bk0, (f32x4){0.f,0.f,0.f,0.f}, 0, 0, 0);
            f32x4 e1 = __builtin_amdgcn_mfma_f32_16x16x32_bf16(aq, bk1, (f32x4){0.f,0.f,0.f,0.f}, 0, 0, 0);
            #pragma unroll
            for (int reg = 0; reg < 4; reg++) {
                float p0 = __expf(e0[reg] * 0.25f);
                float p1 = (lm < V - 16) ? __expf(e1[reg] * 0.25f) : 0.f;
                float pr = p0 + p1;
                pr += __shfl_xor(pr, 1);
                pr += __shfl_xor(pr, 2);
                pr += __shfl_xor(pr, 4);
                pr += __shfl_xor(pr, 8);
                float si = w3 / pr;
                int u = ub + reg;
                int uc = (u < V) ? u : 0;
                float a0v = (u < V) ? (ac1[uc][lm] + si * p0) : 0.f;
                float a1v = (u < V && lm < V - 16) ? (ac1[uc][16 + lm] + si * p1) : 0.f;
                Ainb[(drow0 + reg) * 40 + lm] = f2bf(a0v);
                Ainb[(drow0 + reg) * 40 + 16 + lm] = f2bf(a1v);
            }
        }
        __syncthreads();   // sync4: Ainb written

        // ---- P4: y += Ainb * xwtb  (K=32, acc over s)
        {
            short8 aA = *(const short8*)&Ainb[mrow * 40 + kq * 8];
            #pragma unroll
            for (int nt = 0; nt < 4; nt++) {
                short8 bx8 = *(const short8*)&xwtb[t_ * 2560 + (nt * 16 + lm) * 40 + kq * 8];
                acc[nt] = __builtin_amdgcn_mfma_f32_16x16x32_bf16(aA, bx8, acc[nt], 0, 0, 0);
            }
        }
    }

    // ---- epilogue: BN + residual (from xb, bf16) + relu
    #pragma unroll
    for (int nt = 0; nt < 4; nt++) {
        int o = nt * 16 + lm;
        float g = gs[o], bt_ = bts[o], bsum = bds[o];
        #pragma unroll
        for (int reg = 0; reg < 4; reg++) {
            int grow = drow0 + reg;
            int t = grow >> 5, u = grow & 31;
            if (u < V) {
                float xres = b2f(*(const bf16*)&xb[grow * 72 + o]);
                float yv = fmaxf((acc[nt][reg] + bsum) * g + bt_ + xres, 0.f);
                size_t ob = (size_t)((n * TT + t0 + t) * V + u) * O + o;
                if (f32) ((float*)outp)[ob] = yv;
                else     ((bf16*)outp)[ob] = __float2bfloat16(yv);
            }
        }
    }
}

// ---------------------------------------------------------------------------
extern "C" void kernel_launch(void* const* d_in, const int* in_sizes, int n_in,
                              void* d_out, int out_size, void* d_ws, size_t ws_size,
                              hipStream_t stream) {
    const void* x     = d_in[0];
    const void* A     = d_in[1];
    const void* PA    = d_in[2];
    const void* wA    = d_in[3];
    const void* Wa    = d_in[4];
    const void* ba    = d_in[5];
    const void* Wb    = d_in[6];
    const void* bb    = d_in[7];
    const void* Wd    = d_in[8];
    const void* bd    = d_in[9];
    const void* gamma = d_in[10];
    const void* beta  = d_in[11];

    int*   flagp  = (int*)d_ws;
    float* wsf    = (float*)d_ws;
    float* A_comb = wsf + 64;
    float* S1     = wsf + 64 + 2048;   // reused in-place as A1

    hipMemsetAsync(S1, 0, (size_t)S * NN * V * V * sizeof(float), stream);
    k_detect<<<1, 64, 0, stream>>>(x, flagp);
    k_acomb<<<1, 128, 0, stream>>>(A, PA, wA, A_comb, flagp);
    k_s1<<<dim3(TT / TCH, NN, S), 256, 0, stream>>>(x, Wa, ba, Wb, bb, S1, flagp);
    k_a1<<<S * NN, 64, 0, stream>>>(S1);
    k_main<<<NN * TT / TB, 256, 0, stream>>>(x, Wa, ba, Wb, bb, Wd, bd, gamma, beta, wA,
                                             A_comb, S1, d_out, flagp);
}

// Round 7
// 304.909 us; speedup vs baseline: 3.1548x; 1.1569x over previous
//
#include <hip/hip_runtime.h>
#include <hip/hip_bf16.h>

typedef __hip_bfloat16 bf16;
typedef __attribute__((ext_vector_type(8))) short short8;
typedef __attribute__((ext_vector_type(4))) float f32x4;

#define S  3
#define V  25
#define C  64
#define O  64
#define IC 16
#define NN 32
#define TT 256
#define TB 2
#define TCH 32

__device__ __forceinline__ float b2f(bf16 v) { return __bfloat162float(v); }

__device__ __forceinline__ float ldv(const void* p, size_t i, int f32) {
    return f32 ? ((const float*)p)[i] : b2f(((const bf16*)p)[i]);
}

__device__ __forceinline__ unsigned short f2bf(float f) {
    bf16 h = __float2bfloat16(f);
    return *(unsigned short*)&h;
}

__device__ __forceinline__ void fma4(float4& a, float s, float4 b) {
    a.x += s * b.x; a.y += s * b.y; a.z += s * b.z; a.w += s * b.w;
}

__device__ __forceinline__ float dot16v(const float* a, const float* b) {
    float4 a0 = *(const float4*)(a + 0),  a1 = *(const float4*)(a + 4);
    float4 a2 = *(const float4*)(a + 8),  a3 = *(const float4*)(a + 12);
    float4 b0 = *(const float4*)(b + 0),  b1 = *(const float4*)(b + 4);
    float4 b2 = *(const float4*)(b + 8),  b3 = *(const float4*)(b + 12);
    float e = a0.x*b0.x + a0.y*b0.y + a0.z*b0.z + a0.w*b0.w;
    e += a1.x*b1.x + a1.y*b1.y + a1.z*b1.z + a1.w*b1.w;
    e += a2.x*b2.x + a2.y*b2.y + a2.z*b2.z + a2.w*b2.w;
    e += a3.x*b3.x + a3.y*b3.y + a3.z*b3.z + a3.w*b3.w;
    return e;
}

// ---------------------------------------------------------------------------
__global__ void k_detect(const void* __restrict__ x, int* __restrict__ flag) {
    if (threadIdx.x == 0) {
        const bf16* p = (const bf16*)x;
        int f32 = 0;
        for (int i = 0; i < 2048; i++) {
            float v = b2f(p[i]);
            if (!(v > -1000.f && v < 1000.f)) { f32 = 1; break; }
        }
        *flag = f32;
    }
}

// ---------------------------------------------------------------------------
// k_prep: zero S1; convert weights to bf16 transposed/padded MFMA layouts
// (wprep per s: [watb 16x72 | wbtb 16x72 | wdtb 64x72]); compute A_comb.
// ---------------------------------------------------------------------------
__global__ __launch_bounds__(256) void k_prep(
    const void* __restrict__ A, const void* __restrict__ PA,
    const void* __restrict__ wA,
    const void* __restrict__ Wa, const void* __restrict__ Wb,
    const void* __restrict__ Wd,
    float* __restrict__ A_comb, float* __restrict__ S1,
    unsigned short* __restrict__ wprep, const int* __restrict__ flagp) {
    int f32 = *flagp;
    int g = blockIdx.x * 256 + threadIdx.x;
    int stride = gridDim.x * 256;

    for (int w = g; w < 60000; w += stride) S1[w] = 0.f;

    for (int w = g; w < 3456; w += stride) {           // Wa/Wb -> [i][c] bf16
        int s = w / 1152, r = w % 1152, i = r / 72, c = r % 72;
        unsigned short va = 0, vb = 0;
        if (c < 64) {
            va = f2bf(ldv(Wa, (size_t)s * 1024 + c * 16 + i, f32));
            vb = f2bf(ldv(Wb, (size_t)s * 1024 + c * 16 + i, f32));
        }
        wprep[s * 6912 + i * 72 + c] = va;
        wprep[s * 6912 + 1152 + i * 72 + c] = vb;
    }
    for (int w = g; w < 13824; w += stride) {          // Wd -> [o][c] bf16
        int s = w / 4608, r = w % 4608, o = r / 72, c = r % 72;
        unsigned short vd = 0;
        if (c < 64) vd = f2bf(ldv(Wd, (size_t)s * 4096 + c * 64 + o, f32));
        wprep[s * 6912 + 2304 + o * 72 + c] = vd;
    }

    if (g < S * V) {                                    // A_comb rows
        float w0 = ldv(wA, 0, f32), w1 = ldv(wA, 1, f32);
        float vals[V];
        float m = -1e30f;
        for (int v = 0; v < V; v++) { vals[v] = ldv(PA, g * V + v, f32); m = fmaxf(m, vals[v]); }
        float sum = 0.f;
        for (int v = 0; v < V; v++) { vals[v] = __expf(vals[v] - m); sum += vals[v]; }
        float inv = 1.f / sum;
        for (int v = 0; v < V; v++)
            A_comb[g * V + v] = w0 * ldv(A, g * V + v, f32) + w1 * vals[v] * inv;
    }
}

// ---------------------------------------------------------------------------
// k_s1: unchanged (known-good)
// ---------------------------------------------------------------------------
__global__ __launch_bounds__(256) void k_s1(
    const void* __restrict__ x,
    const void* __restrict__ Wa, const void* __restrict__ ba,
    const void* __restrict__ Wb, const void* __restrict__ bb,
    float* __restrict__ S1g, const int* __restrict__ flagp) {
    int f32 = *flagp;
    int tchunk = blockIdx.x, n = blockIdx.y, s = blockIdx.z;
    int tid = threadIdx.x;

    __shared__ __align__(16) float xs[2][V][68];
    __shared__ __align__(16) float was[C][IC], wbs[C][IC];
    __shared__ __align__(16) float qa[2][V][20], kb[2][V][20];
    __shared__ __align__(16) float bas[IC], bbs[IC];

    if (f32) {
        const float4* Wa4 = (const float4*)Wa + s * 256;
        const float4* Wb4 = (const float4*)Wb + s * 256;
        if (tid < 256) { ((float4*)was)[tid] = Wa4[tid]; ((float4*)wbs)[tid] = Wb4[tid]; }
    } else {
        for (int w = tid; w < 1024; w += 256) {
            ((float*)was)[w] = ldv(Wa, (size_t)s * 1024 + w, 0);
            ((float*)wbs)[w] = ldv(Wb, (size_t)s * 1024 + w, 0);
        }
    }
    if (tid < IC) { bas[tid] = ldv(ba, s * IC + tid, f32); bbs[tid] = ldv(bb, s * IC + tid, f32); }

    float acc[2][2] = {{0.f, 0.f}, {0.f, 0.f}};
    int t0 = tchunk * TCH;
    for (int tt = 0; tt < TCH; tt += 2) {
        __syncthreads();
        if (f32) {
            const float4* xp = (const float4*)x + (size_t)(n * TT + t0 + tt) * 400;
            for (int w = tid; w < 800; w += 256) {
                int t = w / 400, r = w % 400;
                *(float4*)&xs[t][r >> 4][(r & 15) * 4] = xp[w];
            }
        } else {
            size_t base = (size_t)(n * TT + t0 + tt) * V * C;
            for (int w = tid; w < 3200; w += 256)
                xs[w / 1600][(w % 1600) >> 6][w & 63] = ldv(x, base + w, 0);
        }
        __syncthreads();
        if (tid < 100) {
            int u = tid >> 2, iq = tid & 3;
            float4 bq = *(const float4*)&bas[iq * 4];
            float4 bk = *(const float4*)&bbs[iq * 4];
            float4 aq0 = bq, aq1 = bq, ak0 = bk, ak1 = bk;
            #pragma unroll
            for (int c4 = 0; c4 < 16; c4++) {
                float4 xv0 = *(const float4*)&xs[0][u][c4 * 4];
                float4 xv1 = *(const float4*)&xs[1][u][c4 * 4];
                float x0a[4], x1a[4];
                *(float4*)x0a = xv0; *(float4*)x1a = xv1;
                #pragma unroll
                for (int k = 0; k < 4; k++) {
                    float4 wav = *(const float4*)&was[c4 * 4 + k][iq * 4];
                    float4 wbv = *(const float4*)&wbs[c4 * 4 + k][iq * 4];
                    fma4(aq0, x0a[k], wav); fma4(aq1, x1a[k], wav);
                    fma4(ak0, x0a[k], wbv); fma4(ak1, x1a[k], wbv);
                }
            }
            *(float4*)&qa[0][u][iq * 4] = aq0;
            *(float4*)&qa[1][u][iq * 4] = aq1;
            *(float4*)&kb[0][u][iq * 4] = ak0;
            *(float4*)&kb[1][u][iq * 4] = ak1;
        }
        __syncthreads();
        #pragma unroll
        for (int j = 0; j < 2; j++) {
            int w = tid + j * 256;
            if (w < 325) {
                int u = w / 13, v = (w % 13) * 2;
                #pragma unroll
                for (int t = 0; t < 2; t++) {
                    acc[j][0] += dot16v(qa[t][u], kb[t][v]);
                    if (v + 1 < V) acc[j][1] += dot16v(qa[t][u], kb[t][v + 1]);
                }
            }
        }
    }
    #pragma unroll
    for (int j = 0; j < 2; j++) {
        int w = tid + j * 256;
        if (w < 325) {
            int u = w / 13, v = (w % 13) * 2;
            size_t base = (size_t)(s * NN + n) * 625 + u * 25 + v;
            atomicAdd(&S1g[base], acc[j][0]);
            if (v + 1 < V) atomicAdd(&S1g[base + 1], acc[j][1]);
        }
    }
}

// ---------------------------------------------------------------------------
// k_a1: in place S1 row <- A_comb + w2 * softmax(S1row / 64)   (= ac1)
// ---------------------------------------------------------------------------
__global__ void k_a1(float* __restrict__ S1g, const float* __restrict__ A_comb,
                     const void* __restrict__ wA, const int* __restrict__ flagp) {
    int f32 = *flagp;
    float w2 = ldv(wA, 2, f32);
    int sn = blockIdx.x;
    int s = sn / NN;
    int u = threadIdx.x;
    if (u >= V) return;
    float* row = S1g + (size_t)sn * V * V + u * V;
    const float* ac = A_comb + (size_t)(s * V + u) * V;
    const float scale = 1.0f / 64.0f;
    float vals[V];
    float m = -1e30f;
    for (int v = 0; v < V; v++) { vals[v] = row[v] * scale; m = fmaxf(m, vals[v]); }
    float sum = 0.f;
    for (int v = 0; v < V; v++) { vals[v] = __expf(vals[v] - m); sum += vals[v]; }
    float inv = w2 / sum;
    for (int v = 0; v < V; v++) row[v] = ac[v] + vals[v] * inv;
}

// ---------------------------------------------------------------------------
// k_main: round-6 MFMA structure + prefetch-pipelined staging from wprep/ac1g.
//   A-frag: st[m][k], lane m=lane&15, koff=(lane>>4)*8 (short8)
//   B-frag: st[n][k], lane n=lane&15, same koff
//   C/D   : col=lane&15 (+16*nt), row=(lane>>4)*4+reg (+16*wave)
// ---------------------------------------------------------------------------
__global__ __launch_bounds__(256, 3) void k_main(
    const void* __restrict__ x,
    const void* __restrict__ ba, const void* __restrict__ bb,
    const void* __restrict__ bd,
    const void* __restrict__ gamma, const void* __restrict__ beta,
    const void* __restrict__ wA,
    const unsigned short* __restrict__ wprep,
    const float* __restrict__ ac1g,
    void* __restrict__ outp, const int* __restrict__ flagp) {
    int f32 = *flagp;
    int bx = blockIdx.x;
    int n = bx >> 7, tc = bx & 127;
    int t0 = tc * TB;
    int tid = threadIdx.x;
    int lane = tid & 63, wv = tid >> 6;
    int lm = lane & 15, kq = lane >> 4;

    __shared__ __align__(16) unsigned short xb[64 * 72];       // 9216 B
    __shared__ __align__(16) unsigned short wall[6912];        // 13824 B watb|wbtb|wdtb
    __shared__ __align__(16) unsigned short qab[64 * 40];      // 5120 B
    __shared__ __align__(16) unsigned short kbb[64 * 40];      // 5120 B
    __shared__ __align__(16) unsigned short Ainb[64 * 40];     // 5120 B
    __shared__ __align__(16) unsigned short xwtb[2 * 64 * 40]; // 10240 B
    __shared__ __align__(16) float ac1f[640];                  // 2560 B
    __shared__ float gs[O], bts[O], bds[O];                    // 768 B

    unsigned short* watb = wall;
    unsigned short* wbtb = wall + 1152;
    unsigned short* wdtb = wall + 2304;

    // ---- prefetch s=0 staging into registers (issued before x staging)
    uint4 rw[4];
    float ra[3];
    float rbq, rbk;
    {
        const uint4* p = (const uint4*)wprep;
        #pragma unroll
        for (int k = 0; k < 4; k++) {
            int j = tid + k * 256;
            if (j < 864) rw[k] = p[j];
        }
        const float* an = ac1g + (size_t)n * 625;
        #pragma unroll
        for (int k = 0; k < 3; k++) {
            int j = tid + k * 256;
            if (j < 625) ra[k] = an[j];
        }
        rbq = ldv(ba, lm, f32);
        rbk = ldv(bb, lm, f32);
    }

    // ---- stage xb (bf16, rows t*32+u, stride 72)
    if (f32) {
        const float4* xp = (const float4*)x + (size_t)(n * TT + t0) * 400;
        for (int w = tid; w < 800; w += 256) {
            int t = w / 400, r = w % 400, u = r >> 4, c4 = r & 15;
            float4 v = xp[w];
            unsigned short h[4] = {f2bf(v.x), f2bf(v.y), f2bf(v.z), f2bf(v.w)};
            *(uint2*)&xb[(t * 32 + u) * 72 + c4 * 4] = *(uint2*)h;
        }
    } else {
        const unsigned int* xp = (const unsigned int*)x;
        size_t base2 = (size_t)(n * TT + t0) * V * C / 2;
        for (int w = tid; w < 1600; w += 256) {
            int t = w / 800, r = w % 800, u = r >> 5, c2 = r & 31;
            ((unsigned int*)xb)[(t * 32 + u) * 36 + c2] = xp[base2 + (size_t)(t * V + u) * 32 + c2];
        }
    }
    // zero ghost rows u=25..31 (both t)
    for (int w = tid; w < 14 * 36; w += 256) {
        int idx = w / 36, word = w % 36;
        int row = (idx < 7) ? (25 + idx) : (32 + 25 + idx - 7);
        ((unsigned int*)xb)[row * 36 + word] = 0;
    }
    // zero col-pad words 32..35 of real rows
    for (int w = tid; w < 50 * 4; w += 256) {
        int idx = w >> 2, word = 32 + (w & 3);
        int row = (idx < 25) ? idx : (32 + idx - 25);
        ((unsigned int*)xb)[row * 36 + word] = 0;
    }
    // zero qab/kbb k-pad cols 16..31 once
    for (int w = tid; w < 512; w += 256) {
        int r = w >> 3, cw = 8 + (w & 7);
        ((unsigned int*)qab)[r * 20 + cw] = 0;
        ((unsigned int*)kbb)[r * 20 + cw] = 0;
    }
    if (tid < O) {
        bds[tid] = ldv(bd, tid, f32) + ldv(bd, O + tid, f32) + ldv(bd, 2 * O + tid, f32);
        gs[tid] = ldv(gamma, tid, f32) * rsqrtf(1.f + 1e-5f);
        bts[tid] = ldv(beta, tid, f32);
    }
    float w3 = ldv(wA, 3, f32);

    f32x4 acc[4];
    #pragma unroll
    for (int nt = 0; nt < 4; nt++) acc[nt] = (f32x4){0.f, 0.f, 0.f, 0.f};

    int t_ = wv >> 1;
    int mrow = wv * 16 + lm;
    int drow0 = wv * 16 + (kq << 2);
    int ub = ((wv & 1) << 4) + (kq << 2);

    for (int s = 0; s < S; s++) {
        // ---- write prefetched staging to LDS (wall/ac1f not read by P4)
        #pragma unroll
        for (int k = 0; k < 4; k++) {
            int j = tid + k * 256;
            if (j < 864) ((uint4*)wall)[j] = rw[k];
        }
        #pragma unroll
        for (int k = 0; k < 3; k++) {
            int j = tid + k * 256;
            if (j < 625) ac1f[j] = ra[k];
        }
        float bq_c = rbq, bk_c = rbk;
        __syncthreads();   // sync2

        // ---- prefetch s+1 (consumed at next loop top; hidden behind P1-P4)
        if (s < 2) {
            const uint4* p = (const uint4*)wprep + (size_t)(s + 1) * 864;
            #pragma unroll
            for (int k = 0; k < 4; k++) {
                int j = tid + k * 256;
                if (j < 864) rw[k] = p[j];
            }
            const float* an = ac1g + (size_t)((s + 1) * NN + n) * 625;
            #pragma unroll
            for (int k = 0; k < 3; k++) {
                int j = tid + k * 256;
                if (j < 625) ra[k] = an[j];
            }
            rbq = ldv(ba, (s + 1) * IC + lm, f32);
            rbk = ldv(bb, (s + 1) * IC + lm, f32);
        }

        // ---- P1: qa/kb MFMA
        short8 xa0 = *(const short8*)&xb[mrow * 72 + kq * 8];
        short8 xa1 = *(const short8*)&xb[mrow * 72 + 32 + kq * 8];
        {
            short8 wa0 = *(const short8*)&watb[lm * 72 + kq * 8];
            short8 wa1 = *(const short8*)&watb[lm * 72 + 32 + kq * 8];
            short8 wb0 = *(const short8*)&wbtb[lm * 72 + kq * 8];
            short8 wb1 = *(const short8*)&wbtb[lm * 72 + 32 + kq * 8];
            f32x4 q = __builtin_amdgcn_mfma_f32_16x16x32_bf16(xa0, wa0, (f32x4){0.f,0.f,0.f,0.f}, 0, 0, 0);
            q = __builtin_amdgcn_mfma_f32_16x16x32_bf16(xa1, wa1, q, 0, 0, 0);
            f32x4 k = __builtin_amdgcn_mfma_f32_16x16x32_bf16(xa0, wb0, (f32x4){0.f,0.f,0.f,0.f}, 0, 0, 0);
            k = __builtin_amdgcn_mfma_f32_16x16x32_bf16(xa1, wb1, k, 0, 0, 0);
            #pragma unroll
            for (int reg = 0; reg < 4; reg++) {
                qab[(drow0 + reg) * 40 + lm] = f2bf(q[reg] + bq_c);
                kbb[(drow0 + reg) * 40 + lm] = f2bf(k[reg] + bk_c);
            }
        }
        // ---- P3: xw = xb * Wd -> xwtb transposed [t][o][v]
        {
            #pragma unroll
            for (int nt = 0; nt < 4; nt++) {
                short8 wd0 = *(const short8*)&wdtb[(nt * 16 + lm) * 72 + kq * 8];
                short8 wd1 = *(const short8*)&wdtb[(nt * 16 + lm) * 72 + 32 + kq * 8];
                f32x4 xw = __builtin_amdgcn_mfma_f32_16x16x32_bf16(xa0, wd0, (f32x4){0.f,0.f,0.f,0.f}, 0, 0, 0);
                xw = __builtin_amdgcn_mfma_f32_16x16x32_bf16(xa1, wd1, xw, 0, 0, 0);
                unsigned short h[4] = {f2bf(xw[0]), f2bf(xw[1]), f2bf(xw[2]), f2bf(xw[3])};
                *(uint2*)&xwtb[t_ * 2560 + (nt * 16 + lm) * 40 + ub] = *(uint2*)h;
            }
        }
        __syncthreads();   // sync3

        // ---- P2: E MFMA -> exp -> rowsum(shfl) -> combine -> Ainb
        {
            short8 aq = *(const short8*)&qab[mrow * 40 + kq * 8];
            short8 bk0 = *(const short8*)&kbb[(t_ * 32 + lm) * 40 + kq * 8];
            short8 bk1 = *(const short8*)&kbb[(t_ * 32 + 16 + lm) * 40 + kq * 8];
            f32x4 e0 = __builtin_amdgcn_mfma_f32_16x16x32_bf16(aq, bk0, (f32x4){0.f,0.f,0.f,0.f}, 0, 0, 0);
            f32x4 e1 = __builtin_amdgcn_mfma_f32_16x16x32_bf16(aq, bk1, (f32x4){0.f,0.f,0.f,0.f}, 0, 0, 0);
            #pragma unroll
            for (int reg = 0; reg < 4; reg++) {
                float p0 = __expf(e0[reg] * 0.25f);
                float p1 = (lm < V - 16) ? __expf(e1[reg] * 0.25f) : 0.f;
                float pr = p0 + p1;
                pr += __shfl_xor(pr, 1);
                pr += __shfl_xor(pr, 2);
                pr += __shfl_xor(pr, 4);
                pr += __shfl_xor(pr, 8);
                float si = w3 / pr;
                int u = ub + reg;
                int uc = (u < V) ? u : 0;
                float a0v = (u < V) ? (ac1f[uc * 25 + lm] + si * p0) : 0.f;
                float a1v = (u < V && lm < V - 16) ? (ac1f[uc * 25 + 16 + lm] + si * p1) : 0.f;
                Ainb[(drow0 + reg) * 40 + lm] = f2bf(a0v);
                Ainb[(drow0 + reg) * 40 + 16 + lm] = f2bf(a1v);
            }
        }
        __syncthreads();   // sync4

        // ---- P4: y += Ainb * xwtb  (K=32, acc over s)
        {
            short8 aA = *(const short8*)&Ainb[mrow * 40 + kq * 8];
            #pragma unroll
            for (int nt = 0; nt < 4; nt++) {
                short8 bx8 = *(const short8*)&xwtb[t_ * 2560 + (nt * 16 + lm) * 40 + kq * 8];
                acc[nt] = __builtin_amdgcn_mfma_f32_16x16x32_bf16(aA, bx8, acc[nt], 0, 0, 0);
            }
        }
    }

    // ---- epilogue: BN + residual + relu
    #pragma unroll
    for (int nt = 0; nt < 4; nt++) {
        int o = nt * 16 + lm;
        float g = gs[o], bt_ = bts[o], bsum = bds[o];
        #pragma unroll
        for (int reg = 0; reg < 4; reg++) {
            int grow = drow0 + reg;
            int t = grow >> 5, u = grow & 31;
            if (u < V) {
                float xres = b2f(*(const bf16*)&xb[grow * 72 + o]);
                float yv = fmaxf((acc[nt][reg] + bsum) * g + bt_ + xres, 0.f);
                size_t ob = (size_t)((n * TT + t0 + t) * V + u) * O + o;
                if (f32) ((float*)outp)[ob] = yv;
                else     ((bf16*)outp)[ob] = __float2bfloat16(yv);
            }
        }
    }
}

// ---------------------------------------------------------------------------
extern "C" void kernel_launch(void* const* d_in, const int* in_sizes, int n_in,
                              void* d_out, int out_size, void* d_ws, size_t ws_size,
                              hipStream_t stream) {
    const void* x     = d_in[0];
    const void* A     = d_in[1];
    const void* PA    = d_in[2];
    const void* wA    = d_in[3];
    const void* Wa    = d_in[4];
    const void* ba    = d_in[5];
    const void* Wb    = d_in[6];
    const void* bb    = d_in[7];
    const void* Wd    = d_in[8];
    const void* bd    = d_in[9];
    const void* gamma = d_in[10];
    const void* beta  = d_in[11];

    int*   flagp  = (int*)d_ws;
    float* wsf    = (float*)d_ws;
    float* A_comb = wsf + 64;                         // 1875 f
    float* S1     = wsf + 2048;                       // 60000 f (becomes ac1)
    unsigned short* wprep = (unsigned short*)(wsf + 65536);  // 20736 sh

    k_detect<<<1, 64, 0, stream>>>(x, flagp);
    k_prep<<<64, 256, 0, stream>>>(A, PA, wA, Wa, Wb, Wd, A_comb, S1, wprep, flagp);
    k_s1<<<dim3(TT / TCH, NN, S), 256, 0, stream>>>(x, Wa, ba, Wb, bb, S1, flagp);
    k_a1<<<S * NN, 64, 0, stream>>>(S1, A_comb, wA, flagp);
    k_main<<<NN * TT / TB, 256, 0, stream>>>(x, ba, bb, bd, gamma, beta, wA,
                                             wprep, S1, d_out, flagp);
}